// Round 13
// baseline (1799.566 us; speedup 1.0000x reference)
//
#include <hip/hip_runtime.h>
#include <math.h>

#define B_   256
#define C_   2048
#define D_   192
#define EPSf 1e-5f
#define BLAS_Q 384   // OpenBLAS SGEMM_DEFAULT_Q — K-block size (validated in R5)

// ---------------------------------------------------------------------------
// numpy pairwise helpers (validated bit-exact in R5/R8/R10/R11).
// ---------------------------------------------------------------------------
__device__ __forceinline__ float pw96_sq_f4(const float4* a4) {
    float r0 = 0.f, r1 = 0.f, r2 = 0.f, r3 = 0.f, r4 = 0.f, r5 = 0.f, r6 = 0.f, r7 = 0.f;
#pragma unroll
    for (int i = 0; i < 12; ++i) {
        const float4 v0 = a4[2 * i], v1 = a4[2 * i + 1];
        r0 += __fmul_rn(v0.x, v0.x); r1 += __fmul_rn(v0.y, v0.y);
        r2 += __fmul_rn(v0.z, v0.z); r3 += __fmul_rn(v0.w, v0.w);
        r4 += __fmul_rn(v1.x, v1.x); r5 += __fmul_rn(v1.y, v1.y);
        r6 += __fmul_rn(v1.z, v1.z); r7 += __fmul_rn(v1.w, v1.w);
    }
    return ((r0 + r1) + (r2 + r3)) + ((r4 + r5) + (r6 + r7));
}

__device__ __forceinline__ float pw96_sq_s(const float* a) {
    float r0 = 0.f, r1 = 0.f, r2 = 0.f, r3 = 0.f, r4 = 0.f, r5 = 0.f, r6 = 0.f, r7 = 0.f;
#pragma unroll
    for (int i = 0; i < 12; ++i) {
        r0 += __fmul_rn(a[8 * i + 0], a[8 * i + 0]);
        r1 += __fmul_rn(a[8 * i + 1], a[8 * i + 1]);
        r2 += __fmul_rn(a[8 * i + 2], a[8 * i + 2]);
        r3 += __fmul_rn(a[8 * i + 3], a[8 * i + 3]);
        r4 += __fmul_rn(a[8 * i + 4], a[8 * i + 4]);
        r5 += __fmul_rn(a[8 * i + 5], a[8 * i + 5]);
        r6 += __fmul_rn(a[8 * i + 6], a[8 * i + 6]);
        r7 += __fmul_rn(a[8 * i + 7], a[8 * i + 7]);
    }
    return ((r0 + r1) + (r2 + r3)) + ((r4 + r5) + (r6 + r7));
}

// ---------------------------------------------------------------------------
// Batched-compute helpers (register-buffer consumers; FP order == R11 PASS)
// ---------------------------------------------------------------------------
__device__ __forceinline__ void init_comp8(const float4 (&vb)[8],
                                           float (&q)[4][8], float (&s)[4][8]) {
#pragma unroll
    for (int u = 0; u < 8; ++u) {
        q[0][u] += __fmul_rn(vb[u].x, vb[u].x); s[0][u] += vb[u].x;
        q[1][u] += __fmul_rn(vb[u].y, vb[u].y); s[1][u] += vb[u].y;
        q[2][u] += __fmul_rn(vb[u].z, vb[u].z); s[2][u] += vb[u].z;
        q[3][u] += __fmul_rn(vb[u].w, vb[u].w); s[3][u] += vb[u].w;
    }
}

__device__ __forceinline__ void pa_comp8(const float4 (&vb)[8], int dbase,
                                         const float (*cent)[192],
                                         float (&acc)[4][4]) {
#pragma unroll
    for (int u = 0; u < 8; ++u) {
        const int d = dbase + u;
        const float c0 = cent[0][d], c1 = cent[1][d];
        const float c2 = cent[2][d], c3 = cent[3][d];
        acc[0][0] = fmaf(vb[u].x, c0, acc[0][0]);
        acc[1][0] = fmaf(vb[u].y, c0, acc[1][0]);
        acc[2][0] = fmaf(vb[u].z, c0, acc[2][0]);
        acc[3][0] = fmaf(vb[u].w, c0, acc[3][0]);
        acc[0][1] = fmaf(vb[u].x, c1, acc[0][1]);
        acc[1][1] = fmaf(vb[u].y, c1, acc[1][1]);
        acc[2][1] = fmaf(vb[u].z, c1, acc[2][1]);
        acc[3][1] = fmaf(vb[u].w, c1, acc[3][1]);
        acc[0][2] = fmaf(vb[u].x, c2, acc[0][2]);
        acc[1][2] = fmaf(vb[u].y, c2, acc[1][2]);
        acc[2][2] = fmaf(vb[u].z, c2, acc[2][2]);
        acc[3][2] = fmaf(vb[u].w, c2, acc[3][2]);
        acc[0][3] = fmaf(vb[u].x, c3, acc[0][3]);
        acc[1][3] = fmaf(vb[u].y, c3, acc[1][3]);
        acc[2][3] = fmaf(vb[u].z, c3, acc[2][3]);
        acc[3][3] = fmaf(vb[u].w, c3, acc[3][3]);
    }
}

__device__ __forceinline__ void pb_comp8(const float4 (&vb)[8], int cbase,
                                         const unsigned char* ids,
                                         float (&s)[4][4]) {
#pragma unroll
    for (int u = 0; u < 8; ++u) {
        const int id = ids[cbase + u];
        s[0][0] += (id == 0) ? vb[u].x : 0.0f;
        s[1][0] += (id == 0) ? vb[u].y : 0.0f;
        s[2][0] += (id == 0) ? vb[u].z : 0.0f;
        s[3][0] += (id == 0) ? vb[u].w : 0.0f;
        s[0][1] += (id == 1) ? vb[u].x : 0.0f;
        s[1][1] += (id == 1) ? vb[u].y : 0.0f;
        s[2][1] += (id == 1) ? vb[u].z : 0.0f;
        s[3][1] += (id == 1) ? vb[u].w : 0.0f;
        s[0][2] += (id == 2) ? vb[u].x : 0.0f;
        s[1][2] += (id == 2) ? vb[u].y : 0.0f;
        s[2][2] += (id == 2) ? vb[u].z : 0.0f;
        s[3][2] += (id == 2) ? vb[u].w : 0.0f;
        s[0][3] += (id == 3) ? vb[u].x : 0.0f;
        s[1][3] += (id == 3) ? vb[u].y : 0.0f;
        s[2][3] += (id == 3) ? vb[u].z : 0.0f;
        s[3][3] += (id == 3) ? vb[u].w : 0.0f;
    }
}

// ---------------------------------------------------------------------------
// Kernel 0 (fast path): tile-transpose x[b][c][d] -> xT[b][d][c].
// ---------------------------------------------------------------------------
__global__ __launch_bounds__(256) void transpose_kernel(const float* __restrict__ x,
                                                        float* __restrict__ xT) {
    const int b = blockIdx.z, c0 = blockIdx.x * 64, d0 = blockIdx.y * 64;
    const float* X = x + (size_t)b * (C_ * (size_t)D_);
    float* XT      = xT + (size_t)b * (C_ * (size_t)D_);
    __shared__ float tile[64][65];
    const int tx = threadIdx.x & 63, ty = threadIdx.x >> 6;
#pragma unroll
    for (int i = 0; i < 16; ++i) {
        const int c = ty + i * 4;
        tile[c][tx] = X[(size_t)(c0 + c) * D_ + d0 + tx];
    }
    __syncthreads();
#pragma unroll
    for (int i = 0; i < 16; ++i) {
        const int d = ty + i * 4;
        XT[(size_t)(d0 + d) * C_ + c0 + tx] = tile[tx][d];
    }
}

// ---------------------------------------------------------------------------
// Kernel 1 (fast path): fused pool + kmeans, 512 thr/block, 1 block/sample.
// R12 CHANGE vs R11: all streaming loops are software-pipelined with an
// explicit double register buffer (bufA/bufB) — next batch's 8 loads issue
// BEFORE current batch's compute, so the compiler emits counted
// s_waitcnt vmcnt(8) instead of drain-to-zero; 8-16KB/wave stays in flight
// through the compute phases. FP consume order is UNCHANGED (bit-identical
// to R11 PASS); only load issue timing moves.
// ---------------------------------------------------------------------------
__global__ __launch_bounds__(512) void kmeans_fast_kernel(const float* __restrict__ x,
                                                          const float* __restrict__ xT,
                                                          float* __restrict__ pooled,
                                                          unsigned char* __restrict__ ids_out) {
    const int b = blockIdx.x, t = threadIdx.x;
    const int lane = t & 63;
    const float* X   = x  + (size_t)b * (C_ * (size_t)D_);
    const float* XTb = xT + (size_t)b * (C_ * (size_t)D_);

    __shared__ __align__(16) float cent[4][192];
    __shared__ float xs_s[C_];
    __shared__ float part[6][4][192];
    __shared__ float cs4[4];
    __shared__ int   cnt[4];
    __shared__ int   changed;
    __shared__ unsigned char ids[C_];

    if (t < 192) {
        cent[0][t] = X[(size_t)0    * D_ + t];
        cent[1][t] = X[(size_t)512  * D_ + t];
        cent[2][t] = X[(size_t)1024 * D_ + t];
        cent[3][t] = X[(size_t)1536 * D_ + t];
    }

    // ---- init: xs (np pairwise 96+96, 8 accums) + pooled; pipelined ----
    {
        const float4* pA = (const float4*)XTb + t;   // (d, channels 4t..4t+3)
        float sq0 = 0.f, sq1 = 0.f, sq2 = 0.f, sq3 = 0.f;
        float sm0 = 0.f, sm1 = 0.f, sm2 = 0.f, sm3 = 0.f;
#pragma unroll
        for (int blk = 0; blk < 2; ++blk) {
            float q[4][8], s[4][8];
#pragma unroll
            for (int ch = 0; ch < 4; ++ch)
#pragma unroll
                for (int j = 0; j < 8; ++j) { q[ch][j] = 0.f; s[ch][j] = 0.f; }
            float4 bufA[8], bufB[8];
#pragma unroll
            for (int u = 0; u < 8; ++u) bufA[u] = pA[(blk * 96 + u) << 9];
            for (int i = 0; i < 12; i += 2) {
#pragma unroll
                for (int u = 0; u < 8; ++u) bufB[u] = pA[(blk * 96 + 8 * (i + 1) + u) << 9];
                init_comp8(bufA, q, s);
                if (i + 2 < 12) {
#pragma unroll
                    for (int u = 0; u < 8; ++u) bufA[u] = pA[(blk * 96 + 8 * (i + 2) + u) << 9];
                }
                init_comp8(bufB, q, s);
            }
            sq0 += ((q[0][0] + q[0][1]) + (q[0][2] + q[0][3])) + ((q[0][4] + q[0][5]) + (q[0][6] + q[0][7]));
            sq1 += ((q[1][0] + q[1][1]) + (q[1][2] + q[1][3])) + ((q[1][4] + q[1][5]) + (q[1][6] + q[1][7]));
            sq2 += ((q[2][0] + q[2][1]) + (q[2][2] + q[2][3])) + ((q[2][4] + q[2][5]) + (q[2][6] + q[2][7]));
            sq3 += ((q[3][0] + q[3][1]) + (q[3][2] + q[3][3])) + ((q[3][4] + q[3][5]) + (q[3][6] + q[3][7]));
            sm0 += ((s[0][0] + s[0][1]) + (s[0][2] + s[0][3])) + ((s[0][4] + s[0][5]) + (s[0][6] + s[0][7]));
            sm1 += ((s[1][0] + s[1][1]) + (s[1][2] + s[1][3])) + ((s[1][4] + s[1][5]) + (s[1][6] + s[1][7]));
            sm2 += ((s[2][0] + s[2][1]) + (s[2][2] + s[2][3])) + ((s[2][4] + s[2][5]) + (s[2][6] + s[2][7]));
            sm3 += ((s[3][0] + s[3][1]) + (s[3][2] + s[3][3])) + ((s[3][4] + s[3][5]) + (s[3][6] + s[3][7]));
        }
        xs_s[4 * t + 0] = sq0; xs_s[4 * t + 1] = sq1;
        xs_s[4 * t + 2] = sq2; xs_s[4 * t + 3] = sq3;
        *(float4*)(pooled + (size_t)b * C_ + 4 * t) =
            make_float4(sm0 / 192.0f, sm1 / 192.0f, sm2 / 192.0f, sm3 / 192.0f);
        ids[4 * t + 0] = 255; ids[4 * t + 1] = 255;
        ids[4 * t + 2] = 255; ids[4 * t + 3] = 255;
    }
    __syncthreads();

    for (int iter = 0;; ++iter) {
        if (t < 4) {
            cs4[t] = pw96_sq_s(cent[t]) + pw96_sq_s(cent[t] + 96);
            cnt[t] = 0;
        }
        if (t == 0) changed = 0;
        __syncthreads();

        const float q0 = cs4[0], q1 = cs4[1], q2 = cs4[2], q3 = cs4[3];

        // ---- Phase A: 4 channels/thread; pipelined batch-8 loads; chains
        // ascend d=0..191 per (channel, cluster) — R11 rounding order. ----
        int lc0 = 0, lc1 = 0, lc2 = 0, lc3 = 0, mych = 0;
        {
            const float4* pA = (const float4*)XTb + t;
            float acc[4][4] = {};   // [ch][k]
            float4 bufA[8], bufB[8];
#pragma unroll
            for (int u = 0; u < 8; ++u) bufA[u] = pA[u << 9];
            for (int db = 0; db < 192; db += 16) {
#pragma unroll
                for (int u = 0; u < 8; ++u) bufB[u] = pA[(db + 8 + u) << 9];
                pa_comp8(bufA, db, cent, acc);
                if (db + 16 < 192) {
#pragma unroll
                    for (int u = 0; u < 8; ++u) bufA[u] = pA[(db + 16 + u) << 9];
                }
                pa_comp8(bufB, db + 8, cent, acc);
            }
#pragma unroll
            for (int ch = 0; ch < 4; ++ch) {
                const int c = 4 * t + ch;
                const float xv = xs_s[c];
                const float e0 = (xv - 2.0f * acc[ch][0]) + q0;
                const float e1 = (xv - 2.0f * acc[ch][1]) + q1;
                const float e2 = (xv - 2.0f * acc[ch][2]) + q2;
                const float e3 = (xv - 2.0f * acc[ch][3]) + q3;
                int id = 0; float best = e0;
                if (e1 < best) { best = e1; id = 1; }
                if (e2 < best) { best = e2; id = 2; }
                if (e3 < best) { best = e3; id = 3; }
                lc0 += (id == 0); lc1 += (id == 1); lc2 += (id == 2); lc3 += (id == 3);
                mych |= (ids[c] != (unsigned char)id);
                ids[c] = (unsigned char)id;
            }
        }
#pragma unroll
        for (int off = 32; off > 0; off >>= 1) {
            lc0 += __shfl_down(lc0, off);
            lc1 += __shfl_down(lc1, off);
            lc2 += __shfl_down(lc2, off);
            lc3 += __shfl_down(lc3, off);
        }
        if (lane == 0) {
            atomicAdd(&cnt[0], lc0); atomicAdd(&cnt[1], lc1);
            atomicAdd(&cnt[2], lc2); atomicAdd(&cnt[3], lc3);
        }
        if (mych) changed = 1;
        __syncthreads();

        if (changed == 0 || iter == 10) break;   // converged -> exact fixed point

        // ---- Phase B: 288 tasks (kb, dgroup of 4 dims); pipelined batch-8
        // over c; per-(dim,k) chains ascend c within clamped Q=384 blocks. ----
        if (t < 288) {
            const int kb = t / 48;
            const int dg = t - kb * 48;
            const int cb = kb * BLAS_Q;
            const int ce = (cb + BLAS_Q < C_) ? (cb + BLAS_Q) : C_;
            const int nb = (ce - cb) >> 3;          // 48 or 16 (both even)
            const float4* pB = (const float4*)X + (size_t)cb * 48 + dg;
            float s[4][4] = {};   // [dim j][k]
            float4 bufA[8], bufB[8];
#pragma unroll
            for (int u = 0; u < 8; ++u) bufA[u] = pB[(size_t)u * 48];
            for (int ib = 0; ib < nb; ib += 2) {
#pragma unroll
                for (int u = 0; u < 8; ++u) bufB[u] = pB[(size_t)((ib + 1) * 8 + u) * 48];
                pb_comp8(bufA, cb + ib * 8, ids, s);
                if (ib + 2 < nb) {
#pragma unroll
                    for (int u = 0; u < 8; ++u) bufA[u] = pB[(size_t)((ib + 2) * 8 + u) * 48];
                }
                pb_comp8(bufB, cb + (ib + 1) * 8, ids, s);
            }
#pragma unroll
            for (int k = 0; k < 4; ++k) {
                part[kb][k][4 * dg + 0] = s[0][k];
                part[kb][k][4 * dg + 1] = s[1][k];
                part[kb][k][4 * dg + 2] = s[2][k];
                part[kb][k][4 * dg + 3] = s[3][k];
            }
        }
        __syncthreads();
        if (t < 192) {
#pragma unroll
            for (int k = 0; k < 4; ++k) {
                float tt = part[0][k][t];          // = 0 + p0 exactly (R5 order)
                tt += part[1][k][t];
                tt += part[2][k][t];
                tt += part[3][k][t];
                tt += part[4][k][t];
                tt += part[5][k][t];
                if (cnt[k] > 0) cent[k][t] = tt / (float)cnt[k];
            }
        }
        __syncthreads();
    }

    *(uchar4*)(ids_out + (size_t)b * C_ + 4 * t) = *(uchar4*)&ids[4 * t];
}

// ---------------------------------------------------------------------------
// FALLBACK (ws too small): exact R8 PASS kernels.
// ---------------------------------------------------------------------------
__global__ __launch_bounds__(256) void pool_kernel(const float* __restrict__ x,
                                                   float* __restrict__ pooled) {
    const int row  = blockIdx.x * 4 + (threadIdx.x >> 6);
    const int lane = threadIdx.x & 63;
    const float* r = x + (size_t)row * D_;
    float s = 0.f;
    if (lane < 48) {
        const float4 v = ((const float4*)r)[lane];
        s = v.x + v.y + v.z + v.w;
    }
#pragma unroll
    for (int off = 32; off > 0; off >>= 1) s += __shfl_down(s, off);
    if (lane == 0) pooled[row] = s * (1.f / 192.f);
}

__global__ __launch_bounds__(512) void kmeans_fb_kernel(const float* __restrict__ x,
                                                        unsigned char* __restrict__ ids_out) {
    const int b = blockIdx.x, t = threadIdx.x;
    const int lane = t & 63;
    const float* X = x + (size_t)b * (C_ * (size_t)D_);

    __shared__ __align__(16) float cent[4][192];
    __shared__ float xs_s[C_];
    __shared__ float cs4[4];
    __shared__ int   cnt[4];
    __shared__ int   changed;
    __shared__ unsigned char ids[C_];

    if (t < 192) {
        cent[0][t] = X[(size_t)0    * D_ + t];
        cent[1][t] = X[(size_t)512  * D_ + t];
        cent[2][t] = X[(size_t)1024 * D_ + t];
        cent[3][t] = X[(size_t)1536 * D_ + t];
    }
    for (int c = t; c < C_; c += 512) {
        const float4* r4 = (const float4*)(X + (size_t)c * D_);
        xs_s[c] = pw96_sq_f4(r4) + pw96_sq_f4(r4 + 24);
        ids[c]  = 255;
    }
    __syncthreads();

    for (int iter = 0;; ++iter) {
        if (t < 4) {
            cs4[t] = pw96_sq_s(cent[t]) + pw96_sq_s(cent[t] + 96);
            cnt[t] = 0;
        }
        if (t == 0) changed = 0;
        __syncthreads();

        const float q0 = cs4[0], q1 = cs4[1], q2 = cs4[2], q3 = cs4[3];
        int lc0 = 0, lc1 = 0, lc2 = 0, lc3 = 0, mych = 0;
        for (int j = 0; j < 4; ++j) {
            const int c = t + 512 * j;
            const float4* r4 = (const float4*)(X + (size_t)c * D_);
            float d0 = 0.f, d1 = 0.f, d2 = 0.f, d3 = 0.f;
#pragma unroll 8
            for (int i = 0; i < 48; ++i) {
                const float4 a  = r4[i];
                const float4 c0 = *(const float4*)&cent[0][4 * i];
                const float4 c1 = *(const float4*)&cent[1][4 * i];
                const float4 c2 = *(const float4*)&cent[2][4 * i];
                const float4 c3 = *(const float4*)&cent[3][4 * i];
                d0 = fmaf(a.x, c0.x, d0); d0 = fmaf(a.y, c0.y, d0);
                d0 = fmaf(a.z, c0.z, d0); d0 = fmaf(a.w, c0.w, d0);
                d1 = fmaf(a.x, c1.x, d1); d1 = fmaf(a.y, c1.y, d1);
                d1 = fmaf(a.z, c1.z, d1); d1 = fmaf(a.w, c1.w, d1);
                d2 = fmaf(a.x, c2.x, d2); d2 = fmaf(a.y, c2.y, d2);
                d2 = fmaf(a.z, c2.z, d2); d2 = fmaf(a.w, c2.w, d2);
                d3 = fmaf(a.x, c3.x, d3); d3 = fmaf(a.y, c3.y, d3);
                d3 = fmaf(a.z, c3.z, d3); d3 = fmaf(a.w, c3.w, d3);
            }
            const float xv = xs_s[c];
            const float e0 = (xv - 2.0f * d0) + q0;
            const float e1 = (xv - 2.0f * d1) + q1;
            const float e2 = (xv - 2.0f * d2) + q2;
            const float e3 = (xv - 2.0f * d3) + q3;
            int id = 0; float best = e0;
            if (e1 < best) { best = e1; id = 1; }
            if (e2 < best) { best = e2; id = 2; }
            if (e3 < best) { best = e3; id = 3; }
            lc0 += (id == 0); lc1 += (id == 1); lc2 += (id == 2); lc3 += (id == 3);
            mych |= (ids[c] != (unsigned char)id);
            ids[c] = (unsigned char)id;
        }
#pragma unroll
        for (int off = 32; off > 0; off >>= 1) {
            lc0 += __shfl_down(lc0, off);
            lc1 += __shfl_down(lc1, off);
            lc2 += __shfl_down(lc2, off);
            lc3 += __shfl_down(lc3, off);
        }
        if (lane == 0) {
            atomicAdd(&cnt[0], lc0); atomicAdd(&cnt[1], lc1);
            atomicAdd(&cnt[2], lc2); atomicAdd(&cnt[3], lc3);
        }
        if (mych) changed = 1;
        __syncthreads();

        if (changed == 0 || iter == 10) break;

        if (t < 192) {
            float t0 = 0.f, t1 = 0.f, t2 = 0.f, t3 = 0.f;
            for (int kb = 0; kb < C_; kb += BLAS_Q) {
                const int ke = (kb + BLAS_Q < C_) ? (kb + BLAS_Q) : C_;
                float s0 = 0.f, s1 = 0.f, s2 = 0.f, s3 = 0.f;
                for (int c = kb; c < ke; ++c) {
                    const float xv = X[(size_t)c * D_ + t];
                    const int id = ids[c];
                    s0 += (id == 0) ? xv : 0.0f;
                    s1 += (id == 1) ? xv : 0.0f;
                    s2 += (id == 2) ? xv : 0.0f;
                    s3 += (id == 3) ? xv : 0.0f;
                }
                t0 += s0; t1 += s1; t2 += s2; t3 += s3;
            }
            if (cnt[0] > 0) cent[0][t] = t0 / (float)cnt[0];
            if (cnt[1] > 0) cent[1][t] = t1 / (float)cnt[1];
            if (cnt[2] > 0) cent[2][t] = t2 / (float)cnt[2];
            if (cnt[3] > 0) cent[3][t] = t3 / (float)cnt[3];
        }
        __syncthreads();
    }

    for (int c = t; c < C_; c += 512) ids_out[(size_t)b * C_ + c] = ids[c];
}

// ---------------------------------------------------------------------------
__device__ __forceinline__ float bn_apply(float v, float g, float be, float m, float va) {
    return (v - m) / sqrtf(va + EPSf) * g + be;
}

// ---------------------------------------------------------------------------
// Kernel 3: batched 64x64-tiled GEMM, M=256, N=512, K=2048.
// ---------------------------------------------------------------------------
__global__ __launch_bounds__(256) void gemm1_kernel(
    const float* __restrict__ pooled, const unsigned char* __restrict__ ids,
    const float* __restrict__ Wg, const float* __restrict__ bg,
    const float* __restrict__ g_gamma, const float* __restrict__ g_beta,
    const float* __restrict__ g_mean, const float* __restrict__ g_var,
    const float* __restrict__ gb_gamma, const float* __restrict__ gb_beta,
    const float* __restrict__ gb_mean, const float* __restrict__ gb_var,
    const float* __restrict__ W1, const float* __restrict__ b1,
    const float* __restrict__ n1_gamma, const float* __restrict__ n1_beta,
    const float* __restrict__ n1_mean, const float* __restrict__ n1_var,
    float* __restrict__ xg2, float* __restrict__ h1) {
    const int z = blockIdx.z;
    const int bn0 = blockIdx.x * 64, bm0 = blockIdx.y * 64;
    const float* Bmat = (z == 0) ? Wg : W1;
    __shared__ float As[32][68];
    __shared__ float Bs[32][68];
    float acc[4][4] = {};
    const int t = threadIdx.x;
    const int tx = t & 15, ty = t >> 4;

    for (int k0 = 0; k0 < 2048; k0 += 32) {
#pragma unroll
        for (int u = 0; u < 2; ++u) {
            const int idx = t + 256 * u;
            const int m = idx >> 3, kc = idx & 7;
            float4 v = *(const float4*)(pooled + (size_t)(bm0 + m) * 2048 + k0 + kc * 4);
            if (z > 0) {
                const unsigned int uu =
                    *(const unsigned int*)(ids + (size_t)(bm0 + m) * 2048 + k0 + kc * 4);
                const unsigned int k = (unsigned int)(z - 1);
                v.x = ((uu & 0xffu) == k) ? v.x : 0.f;
                v.y = (((uu >> 8) & 0xffu) == k) ? v.y : 0.f;
                v.z = (((uu >> 16) & 0xffu) == k) ? v.z : 0.f;
                v.w = (((uu >> 24) & 0xffu) == k) ? v.w : 0.f;
            }
            As[kc * 4 + 0][m] = v.x; As[kc * 4 + 1][m] = v.y;
            As[kc * 4 + 2][m] = v.z; As[kc * 4 + 3][m] = v.w;
            const float4 wv = *(const float4*)(Bmat + (size_t)(bn0 + m) * 2048 + k0 + kc * 4);
            Bs[kc * 4 + 0][m] = wv.x; Bs[kc * 4 + 1][m] = wv.y;
            Bs[kc * 4 + 2][m] = wv.z; Bs[kc * 4 + 3][m] = wv.w;
        }
        __syncthreads();
#pragma unroll 8
        for (int kk = 0; kk < 32; ++kk) {
            const float4 a = *(const float4*)&As[kk][ty * 4];
            const float4 wv = *(const float4*)&Bs[kk][tx * 4];
            const float av[4] = {a.x, a.y, a.z, a.w};
            const float bv[4] = {wv.x, wv.y, wv.z, wv.w};
#pragma unroll
            for (int i = 0; i < 4; ++i)
#pragma unroll
                for (int j = 0; j < 4; ++j) acc[i][j] += av[i] * bv[j];
        }
        __syncthreads();
    }

    const int m0 = bm0 + ty * 4, n0 = bn0 + tx * 4;
    if (z == 0) {
#pragma unroll
        for (int j = 0; j < 4; ++j) {
            const int n = n0 + j;
            const float bgv = bg[n];
            const float g1 = g_gamma[n], be1 = g_beta[n], mm1 = g_mean[n], vv1 = g_var[n];
            const float g2 = gb_gamma[n], be2 = gb_beta[n], mm2 = gb_mean[n], vv2 = gb_var[n];
#pragma unroll
            for (int i = 0; i < 4; ++i) {
                float v = acc[i][j] + bgv;
                v = bn_apply(v, g1, be1, mm1, vv1);
                v = fmaxf(v, 0.f);
                v = bn_apply(v, g2, be2, mm2, vv2);
                xg2[(size_t)(m0 + i) * 512 + n] = v;
            }
        }
    } else {
        const int k = z - 1;
#pragma unroll
        for (int j = 0; j < 4; ++j) {
            const int n = n0 + j;
            const float b1v = b1[n];
            const float g1 = n1_gamma[n], be1 = n1_beta[n], mm1 = n1_mean[n], vv1 = n1_var[n];
#pragma unroll
            for (int i = 0; i < 4; ++i) {
                float v = acc[i][j] + b1v;
                v = bn_apply(v, g1, be1, mm1, vv1);
                v = fmaxf(v, 0.f);
                h1[((size_t)k * 256 + (m0 + i)) * 512 + n] = v;
            }
        }
    }
}

// ---------------------------------------------------------------------------
// Kernel 4
// ---------------------------------------------------------------------------
__global__ __launch_bounds__(256) void gemm2_kernel(
    const float* __restrict__ h1, const float* __restrict__ W2,
    const float* __restrict__ b2,
    const float* __restrict__ n2_gamma, const float* __restrict__ n2_beta,
    const float* __restrict__ n2_mean, const float* __restrict__ n2_var,
    const float* __restrict__ bk_gamma, const float* __restrict__ bk_beta,
    const float* __restrict__ bk_mean, const float* __restrict__ bk_var,
    float* __restrict__ yv) {
    const int bn0 = blockIdx.x * 64, bm0 = blockIdx.y * 64;
    __shared__ float As[32][68];
    __shared__ float Bs[32][68];
    float acc[4][4] = {};
    const int t = threadIdx.x;
    const int tx = t & 15, ty = t >> 4;

    for (int k0 = 0; k0 < 512; k0 += 32) {
#pragma unroll
        for (int u = 0; u < 2; ++u) {
            const int idx = t + 256 * u;
            const int m = idx >> 3, kc = idx & 7;
            const float4 v = *(const float4*)(h1 + (size_t)(bm0 + m) * 512 + k0 + kc * 4);
            As[kc * 4 + 0][m] = v.x; As[kc * 4 + 1][m] = v.y;
            As[kc * 4 + 2][m] = v.z; As[kc * 4 + 3][m] = v.w;
            const float4 wv = *(const float4*)(W2 + (size_t)(bn0 + m) * 512 + k0 + kc * 4);
            Bs[kc * 4 + 0][m] = wv.x; Bs[kc * 4 + 1][m] = wv.y;
            Bs[kc * 4 + 2][m] = wv.z; Bs[kc * 4 + 3][m] = wv.w;
        }
        __syncthreads();
#pragma unroll 8
        for (int kk = 0; kk < 32; ++kk) {
            const float4 a = *(const float4*)&As[kk][ty * 4];
            const float4 wv = *(const float4*)&Bs[kk][tx * 4];
            const float av[4] = {a.x, a.y, a.z, a.w};
            const float bv[4] = {wv.x, wv.y, wv.z, wv.w};
#pragma unroll
            for (int i = 0; i < 4; ++i)
#pragma unroll
                for (int j = 0; j < 4; ++j) acc[i][j] += av[i] * bv[j];
        }
        __syncthreads();
    }

    const int m0 = bm0 + ty * 4, n0 = bn0 + tx * 4;
#pragma unroll
    for (int j = 0; j < 4; ++j) {
        const int n = n0 + j;
        const float b2v = b2[n];
        const float g1 = n2_gamma[n], be1 = n2_beta[n], mm1 = n2_mean[n], vv1 = n2_var[n];
#pragma unroll
        for (int i = 0; i < 4; ++i) {
            const int row = m0 + i;
            const int k = row >> 8, b = row & 255;
            float v = acc[i][j] + b2v;
            v = bn_apply(v, g1, be1, mm1, vv1);
            v = fmaxf(v, 0.f);
            const int pi = k * 128 + n;
            v = bn_apply(v, bk_gamma[pi], bk_beta[pi], bk_mean[pi], bk_var[pi]);
            yv[(size_t)b * 512 + pi] = v;
        }
    }
}

// ---------------------------------------------------------------------------
// Kernel 5: heads
// ---------------------------------------------------------------------------
__global__ __launch_bounds__(128) void head_kernel(
    const float* __restrict__ xg2, const float* __restrict__ yv,
    const float* __restrict__ Wcg, const float* __restrict__ bcg,
    const float* __restrict__ Wck, const float* __restrict__ bck,
    float* __restrict__ out) {
    const int b = blockIdx.x, t = threadIdx.x;
    __shared__ float xr[512], yr[512];
    ((float4*)xr)[t] = ((const float4*)(xg2 + (size_t)b * 512))[t];
    ((float4*)yr)[t] = ((const float4*)(yv + (size_t)b * 512))[t];
    __syncthreads();
    if (t < 51) {
        float acc = 0.f;
        const float4* wr = (const float4*)(Wcg + (size_t)t * 512);
        const float4* xv = (const float4*)xr;
#pragma unroll 8
        for (int p = 0; p < 128; ++p) {
            const float4 w4 = wr[p], v4 = xv[p];
            acc += w4.x * v4.x + w4.y * v4.y + w4.z * v4.z + w4.w * v4.w;
        }
        out[(size_t)b * 51 + t] = acc + bcg[t];
    } else if (t >= 64 && t < 115) {
        const int n = t - 64;
        float acc = 0.f;
        const float4* wr = (const float4*)(Wck + (size_t)n * 512);
        const float4* yv4 = (const float4*)yr;
#pragma unroll 8
        for (int p = 0; p < 128; ++p) {
            const float4 w4 = wr[p], v4 = yv4[p];
            acc += w4.x * v4.x + w4.y * v4.y + w4.z * v4.z + w4.w * v4.w;
        }
        out[(size_t)(B_ * 51) + (size_t)b * 51 + n] = acc + bck[n];
    }
}

// ---------------------------------------------------------------------------
extern "C" void kernel_launch(void* const* d_in, const int* in_sizes, int n_in,
                              void* d_out, int out_size, void* d_ws, size_t ws_size,
                              hipStream_t stream) {
    const float* x        = (const float*)d_in[0];
    const float* Wg       = (const float*)d_in[1];
    const float* bg       = (const float*)d_in[2];
    const float* g_gamma  = (const float*)d_in[3];
    const float* g_beta   = (const float*)d_in[4];
    const float* g_mean   = (const float*)d_in[5];
    const float* g_var    = (const float*)d_in[6];
    const float* gb_gamma = (const float*)d_in[7];
    const float* gb_beta  = (const float*)d_in[8];
    const float* gb_mean  = (const float*)d_in[9];
    const float* gb_var   = (const float*)d_in[10];
    const float* Wcg      = (const float*)d_in[11];
    const float* bcg      = (const float*)d_in[12];
    const float* W1       = (const float*)d_in[13];
    const float* b1       = (const float*)d_in[14];
    const float* n1_gamma = (const float*)d_in[15];
    const float* n1_beta  = (const float*)d_in[16];
    const float* n1_mean  = (const float*)d_in[17];
    const float* n1_var   = (const float*)d_in[18];
    const float* W2       = (const float*)d_in[19];
    const float* b2       = (const float*)d_in[20];
    const float* n2_gamma = (const float*)d_in[21];
    const float* n2_beta  = (const float*)d_in[22];
    const float* n2_mean  = (const float*)d_in[23];
    const float* n2_var   = (const float*)d_in[24];
    const float* bk_gamma = (const float*)d_in[25];
    const float* bk_beta  = (const float*)d_in[26];
    const float* bk_mean  = (const float*)d_in[27];
    const float* bk_var   = (const float*)d_in[28];
    const float* Wck      = (const float*)d_in[29];
    const float* bck      = (const float*)d_in[30];
    float* out = (float*)d_out;

    const size_t xt_elems    = (size_t)B_ * C_ * D_;              // 100,663,296 floats
    const size_t small_elems = 524288 + 131072 + 524288 + 131072; // pooled,xg2,h1,yv
    const size_t need_fast   = xt_elems * 4 + small_elems * 4 + 524288 + 256;

    if (ws_size >= need_fast) {
        float* xT          = (float*)d_ws;
        float* pooled      = xT + xt_elems;                      // 524288 f
        unsigned char* ids = (unsigned char*)(pooled + 524288);  // 524288 B
        float* xg2         = (float*)(ids + 524288);             // 131072 f
        float* h1          = xg2 + 131072;                       // 524288 f
        float* yv          = h1 + 524288;                        // 131072 f

        transpose_kernel<<<dim3(32, 3, B_), dim3(256), 0, stream>>>(x, xT);
        kmeans_fast_kernel<<<dim3(B_), dim3(512), 0, stream>>>(x, xT, pooled, ids);
        gemm1_kernel<<<dim3(8, 4, 5), dim3(256), 0, stream>>>(
            pooled, ids, Wg, bg, g_gamma, g_beta, g_mean, g_var,
            gb_gamma, gb_beta, gb_mean, gb_var, W1, b1,
            n1_gamma, n1_beta, n1_mean, n1_var, xg2, h1);
        gemm2_kernel<<<dim3(2, 16), dim3(256), 0, stream>>>(
            h1, W2, b2, n2_gamma, n2_beta, n2_mean, n2_var,
            bk_gamma, bk_beta, bk_mean, bk_var, yv);
        head_kernel<<<dim3(B_), dim3(128), 0, stream>>>(xg2, yv, Wcg, bcg, Wck, bck, out);
    } else {
        float* pooled      = (float*)d_ws;                       // 524288 f
        unsigned char* ids = (unsigned char*)(pooled + 524288);  // 524288 B
        float* xg2         = (float*)(ids + 524288);             // 131072 f
        float* h1          = xg2 + 131072;                       // 524288 f
        float* yv          = h1 + 524288;                        // 131072 f

        pool_kernel<<<dim3((B_ * C_) / 4), dim3(256), 0, stream>>>(x, pooled);
        kmeans_fb_kernel<<<dim3(B_), dim3(512), 0, stream>>>(x, ids);
        gemm1_kernel<<<dim3(8, 4, 5), dim3(256), 0, stream>>>(
            pooled, ids, Wg, bg, g_gamma, g_beta, g_mean, g_var,
            gb_gamma, gb_beta, gb_mean, gb_var, W1, b1,
            n1_gamma, n1_beta, n1_mean, n1_var, xg2, h1);
        gemm2_kernel<<<dim3(2, 16), dim3(256), 0, stream>>>(
            h1, W2, b2, n2_gamma, n2_beta, n2_mean, n2_var,
            bk_gamma, bk_beta, bk_mean, bk_var, yv);
        head_kernel<<<dim3(B_), dim3(128), 0, stream>>>(xg2, yv, Wcg, bcg, Wck, bck, out);
    }
}

// Round 14
// 1748.627 us; speedup vs baseline: 1.0291x; 1.0291x over previous
//
#include <hip/hip_runtime.h>
#include <math.h>

#define B_   256
#define C_   2048
#define D_   192
#define EPSf 1e-5f
#define BLAS_Q 384   // OpenBLAS SGEMM_DEFAULT_Q — K-block size (validated in R5)

// ---------------------------------------------------------------------------
// numpy pairwise helpers (validated bit-exact in R5/R8/R10/R11/R13).
// ---------------------------------------------------------------------------
__device__ __forceinline__ float pw96_sq_f4(const float4* a4) {
    float r0 = 0.f, r1 = 0.f, r2 = 0.f, r3 = 0.f, r4 = 0.f, r5 = 0.f, r6 = 0.f, r7 = 0.f;
#pragma unroll
    for (int i = 0; i < 12; ++i) {
        const float4 v0 = a4[2 * i], v1 = a4[2 * i + 1];
        r0 += __fmul_rn(v0.x, v0.x); r1 += __fmul_rn(v0.y, v0.y);
        r2 += __fmul_rn(v0.z, v0.z); r3 += __fmul_rn(v0.w, v0.w);
        r4 += __fmul_rn(v1.x, v1.x); r5 += __fmul_rn(v1.y, v1.y);
        r6 += __fmul_rn(v1.z, v1.z); r7 += __fmul_rn(v1.w, v1.w);
    }
    return ((r0 + r1) + (r2 + r3)) + ((r4 + r5) + (r6 + r7));
}

__device__ __forceinline__ float pw96_sq_s(const float* a) {
    float r0 = 0.f, r1 = 0.f, r2 = 0.f, r3 = 0.f, r4 = 0.f, r5 = 0.f, r6 = 0.f, r7 = 0.f;
#pragma unroll
    for (int i = 0; i < 12; ++i) {
        r0 += __fmul_rn(a[8 * i + 0], a[8 * i + 0]);
        r1 += __fmul_rn(a[8 * i + 1], a[8 * i + 1]);
        r2 += __fmul_rn(a[8 * i + 2], a[8 * i + 2]);
        r3 += __fmul_rn(a[8 * i + 3], a[8 * i + 3]);
        r4 += __fmul_rn(a[8 * i + 4], a[8 * i + 4]);
        r5 += __fmul_rn(a[8 * i + 5], a[8 * i + 5]);
        r6 += __fmul_rn(a[8 * i + 6], a[8 * i + 6]);
        r7 += __fmul_rn(a[8 * i + 7], a[8 * i + 7]);
    }
    return ((r0 + r1) + (r2 + r3)) + ((r4 + r5) + (r6 + r7));
}

__device__ __forceinline__ float pw96_sum_s(const float* a) {
    float r0 = 0.f, r1 = 0.f, r2 = 0.f, r3 = 0.f, r4 = 0.f, r5 = 0.f, r6 = 0.f, r7 = 0.f;
#pragma unroll
    for (int i = 0; i < 12; ++i) {
        r0 += a[8 * i + 0]; r1 += a[8 * i + 1];
        r2 += a[8 * i + 2]; r3 += a[8 * i + 3];
        r4 += a[8 * i + 4]; r5 += a[8 * i + 5];
        r6 += a[8 * i + 6]; r7 += a[8 * i + 7];
    }
    return ((r0 + r1) + (r2 + r3)) + ((r4 + r5) + (r6 + r7));
}

// ---------------------------------------------------------------------------
// Kernel 0 (fast path): fused transpose + xs + pooled.
// Block = (sample, 64-channel tile). Stages 64x192 floats in LDS (row pad
// 193 -> conflict-free), computes per-channel xs (exact pw96 chains) and
// pooled (np-pairwise sum / 192), writes xT[b][d][c] coalesced.
// ---------------------------------------------------------------------------
__global__ __launch_bounds__(256) void transpose_kernel(const float* __restrict__ x,
                                                        float* __restrict__ xT,
                                                        float* __restrict__ pooled,
                                                        float* __restrict__ xs_g) {
    const int c0 = blockIdx.x * 64, b = blockIdx.y;
    const float* X = x + (size_t)b * (C_ * (size_t)D_);
    float* XT      = xT + (size_t)b * (C_ * (size_t)D_);
    __shared__ float lds[64 * 193];
    const int t = threadIdx.x;

    // load 64 rows x 192 floats (3072 float4)
#pragma unroll
    for (int i = 0; i < 12; ++i) {
        const int idx = i * 256 + t;          // [0, 3072)
        const int r = idx / 48, j = idx % 48;
        const float4 v = *(const float4*)(X + (size_t)(c0 + r) * D_ + 4 * j);
        float* p = &lds[r * 193 + 4 * j];
        p[0] = v.x; p[1] = v.y; p[2] = v.z; p[3] = v.w;
    }
    __syncthreads();

    if (t < 64) {
        const float* row = &lds[t * 193];
        xs_g[(size_t)b * C_ + c0 + t]   = pw96_sq_s(row)  + pw96_sq_s(row + 96);
        pooled[(size_t)b * C_ + c0 + t] = (pw96_sum_s(row) + pw96_sum_s(row + 96)) / 192.0f;
    }

    // write transposed: 192 d-rows x 64 ch = 12288 floats
#pragma unroll
    for (int i = 0; i < 48; ++i) {
        const int idx = i * 256 + t;          // [0, 12288)
        const int d = idx >> 6, ch = idx & 63;
        XT[(size_t)d * C_ + c0 + ch] = lds[ch * 193 + d];
    }
}

// ---------------------------------------------------------------------------
// Batched-compute helpers (float2; FP chain order per channel == R13 PASS)
// ---------------------------------------------------------------------------
__device__ __forceinline__ void pa_comp8_f2(const float2 (&vb)[8], int dbase,
                                            const float (*cent)[192],
                                            float (&acc)[2][4]) {
#pragma unroll
    for (int u = 0; u < 8; ++u) {
        const int d = dbase + u;
        const float c0 = cent[0][d], c1 = cent[1][d];
        const float c2 = cent[2][d], c3 = cent[3][d];
        acc[0][0] = fmaf(vb[u].x, c0, acc[0][0]);
        acc[1][0] = fmaf(vb[u].y, c0, acc[1][0]);
        acc[0][1] = fmaf(vb[u].x, c1, acc[0][1]);
        acc[1][1] = fmaf(vb[u].y, c1, acc[1][1]);
        acc[0][2] = fmaf(vb[u].x, c2, acc[0][2]);
        acc[1][2] = fmaf(vb[u].y, c2, acc[1][2]);
        acc[0][3] = fmaf(vb[u].x, c3, acc[0][3]);
        acc[1][3] = fmaf(vb[u].y, c3, acc[1][3]);
    }
}

__device__ __forceinline__ void pb_comp8_f2(const float2 (&vb)[8], int cbase,
                                            const unsigned char* ids,
                                            float (&s)[2][4]) {
#pragma unroll
    for (int u = 0; u < 8; ++u) {
        const int id = ids[cbase + u];
        s[0][0] += (id == 0) ? vb[u].x : 0.0f;
        s[1][0] += (id == 0) ? vb[u].y : 0.0f;
        s[0][1] += (id == 1) ? vb[u].x : 0.0f;
        s[1][1] += (id == 1) ? vb[u].y : 0.0f;
        s[0][2] += (id == 2) ? vb[u].x : 0.0f;
        s[1][2] += (id == 2) ? vb[u].y : 0.0f;
        s[0][3] += (id == 3) ? vb[u].x : 0.0f;
        s[1][3] += (id == 3) ? vb[u].y : 0.0f;
    }
}

// ---------------------------------------------------------------------------
// Kernel 1 (fast path): kmeans, 1024 thr/block (16 waves/CU), 1 block/sample.
// Phase A: 2 channels/thread (2t, 2t+1) via float2 from xT, batch-8
// double-buffered; per-channel chains ascend d=0..191 — bit-identical to R13.
// Phase B: 576 float2 tasks (kb, dim-pair), ascending c within clamped Q=384
// blocks — bit-identical. xs precomputed by transpose kernel.
// ---------------------------------------------------------------------------
__global__ __launch_bounds__(1024) void kmeans_fast_kernel(const float* __restrict__ x,
                                                           const float* __restrict__ xT,
                                                           const float* __restrict__ xs_g,
                                                           unsigned char* __restrict__ ids_out) {
    const int b = blockIdx.x, t = threadIdx.x;
    const int lane = t & 63;
    const float* X   = x  + (size_t)b * (C_ * (size_t)D_);
    const float* XTb = xT + (size_t)b * (C_ * (size_t)D_);

    __shared__ __align__(16) float cent[4][192];
    __shared__ float xs_s[C_];
    __shared__ float part[6][4][192];
    __shared__ float cs4[4];
    __shared__ int   cnt[4];
    __shared__ int   changed;
    __shared__ unsigned char ids[C_];

    if (t < 192) {
        cent[0][t] = X[(size_t)0    * D_ + t];
        cent[1][t] = X[(size_t)512  * D_ + t];
        cent[2][t] = X[(size_t)1024 * D_ + t];
        cent[3][t] = X[(size_t)1536 * D_ + t];
    }
    {
        const int c2 = 2 * t;
        const float2 xv2 = *(const float2*)(xs_g + (size_t)b * C_ + c2);
        xs_s[c2] = xv2.x; xs_s[c2 + 1] = xv2.y;
        ids[c2] = 255; ids[c2 + 1] = 255;
    }
    __syncthreads();

    for (int iter = 0;; ++iter) {
        if (t < 4) {
            cs4[t] = pw96_sq_s(cent[t]) + pw96_sq_s(cent[t] + 96);
            cnt[t] = 0;
        }
        if (t == 0) changed = 0;
        __syncthreads();

        const float q0 = cs4[0], q1 = cs4[1], q2 = cs4[2], q3 = cs4[3];

        // ---- Phase A: channels 2t, 2t+1; pipelined batch-8 float2 ----
        int lc0 = 0, lc1 = 0, lc2 = 0, lc3 = 0, mych = 0;
        {
            const float2* pA = (const float2*)XTb + t;   // stride per d = 1024 f2
            float acc[2][4] = {};
            float2 bufA[8], bufB[8];
#pragma unroll
            for (int u = 0; u < 8; ++u) bufA[u] = pA[(size_t)u << 10];
            for (int db = 0; db < 192; db += 16) {
#pragma unroll
                for (int u = 0; u < 8; ++u) bufB[u] = pA[(size_t)(db + 8 + u) << 10];
                pa_comp8_f2(bufA, db, cent, acc);
                if (db + 16 < 192) {
#pragma unroll
                    for (int u = 0; u < 8; ++u) bufA[u] = pA[(size_t)(db + 16 + u) << 10];
                }
                pa_comp8_f2(bufB, db + 8, cent, acc);
            }
#pragma unroll
            for (int ch = 0; ch < 2; ++ch) {
                const int c = 2 * t + ch;
                const float xv = xs_s[c];
                const float e0 = (xv - 2.0f * acc[ch][0]) + q0;
                const float e1 = (xv - 2.0f * acc[ch][1]) + q1;
                const float e2 = (xv - 2.0f * acc[ch][2]) + q2;
                const float e3 = (xv - 2.0f * acc[ch][3]) + q3;
                int id = 0; float best = e0;
                if (e1 < best) { best = e1; id = 1; }
                if (e2 < best) { best = e2; id = 2; }
                if (e3 < best) { best = e3; id = 3; }
                lc0 += (id == 0); lc1 += (id == 1); lc2 += (id == 2); lc3 += (id == 3);
                mych |= (ids[c] != (unsigned char)id);
                ids[c] = (unsigned char)id;
            }
        }
#pragma unroll
        for (int off = 32; off > 0; off >>= 1) {
            lc0 += __shfl_down(lc0, off);
            lc1 += __shfl_down(lc1, off);
            lc2 += __shfl_down(lc2, off);
            lc3 += __shfl_down(lc3, off);
        }
        if (lane == 0) {
            atomicAdd(&cnt[0], lc0); atomicAdd(&cnt[1], lc1);
            atomicAdd(&cnt[2], lc2); atomicAdd(&cnt[3], lc3);
        }
        if (mych) changed = 1;
        __syncthreads();

        if (changed == 0 || iter == 10) break;   // converged -> exact fixed point

        // ---- Phase B: 576 tasks (kb, dim-pair); pipelined batch-8 float2;
        // per-(dim,k) chains ascend c within clamped Q=384 blocks. ----
        if (t < 576) {
            const int kb = t / 96;
            const int dg = t - kb * 96;           // dims 2dg, 2dg+1
            const int cb = kb * BLAS_Q;
            const int ce = (cb + BLAS_Q < C_) ? (cb + BLAS_Q) : C_;
            const int nb = (ce - cb) >> 3;        // 48 or 16 (both even)
            const float2* pB = (const float2*)X + (size_t)cb * 96 + dg;
            float s[2][4] = {};
            float2 bufA[8], bufB[8];
#pragma unroll
            for (int u = 0; u < 8; ++u) bufA[u] = pB[(size_t)u * 96];
            for (int ib = 0; ib < nb; ib += 2) {
#pragma unroll
                for (int u = 0; u < 8; ++u) bufB[u] = pB[(size_t)((ib + 1) * 8 + u) * 96];
                pb_comp8_f2(bufA, cb + ib * 8, ids, s);
                if (ib + 2 < nb) {
#pragma unroll
                    for (int u = 0; u < 8; ++u) bufA[u] = pB[(size_t)((ib + 2) * 8 + u) * 96];
                }
                pb_comp8_f2(bufB, cb + (ib + 1) * 8, ids, s);
            }
#pragma unroll
            for (int k = 0; k < 4; ++k) {
                part[kb][k][2 * dg + 0] = s[0][k];
                part[kb][k][2 * dg + 1] = s[1][k];
            }
        }
        __syncthreads();
        if (t < 192) {
#pragma unroll
            for (int k = 0; k < 4; ++k) {
                float tt = part[0][k][t];          // = 0 + p0 exactly (R5 order)
                tt += part[1][k][t];
                tt += part[2][k][t];
                tt += part[3][k][t];
                tt += part[4][k][t];
                tt += part[5][k][t];
                if (cnt[k] > 0) cent[k][t] = tt / (float)cnt[k];
            }
        }
        __syncthreads();
    }

    *(uchar2*)(ids_out + (size_t)b * C_ + 2 * t) = *(uchar2*)&ids[2 * t];
}

// ---------------------------------------------------------------------------
// FALLBACK (ws too small): exact R8 PASS kernels.
// ---------------------------------------------------------------------------
__global__ __launch_bounds__(256) void pool_kernel(const float* __restrict__ x,
                                                   float* __restrict__ pooled) {
    const int row  = blockIdx.x * 4 + (threadIdx.x >> 6);
    const int lane = threadIdx.x & 63;
    const float* r = x + (size_t)row * D_;
    float s = 0.f;
    if (lane < 48) {
        const float4 v = ((const float4*)r)[lane];
        s = v.x + v.y + v.z + v.w;
    }
#pragma unroll
    for (int off = 32; off > 0; off >>= 1) s += __shfl_down(s, off);
    if (lane == 0) pooled[row] = s * (1.f / 192.f);
}

__global__ __launch_bounds__(512) void kmeans_fb_kernel(const float* __restrict__ x,
                                                        unsigned char* __restrict__ ids_out) {
    const int b = blockIdx.x, t = threadIdx.x;
    const int lane = t & 63;
    const float* X = x + (size_t)b * (C_ * (size_t)D_);

    __shared__ __align__(16) float cent[4][192];
    __shared__ float xs_s[C_];
    __shared__ float cs4[4];
    __shared__ int   cnt[4];
    __shared__ int   changed;
    __shared__ unsigned char ids[C_];

    if (t < 192) {
        cent[0][t] = X[(size_t)0    * D_ + t];
        cent[1][t] = X[(size_t)512  * D_ + t];
        cent[2][t] = X[(size_t)1024 * D_ + t];
        cent[3][t] = X[(size_t)1536 * D_ + t];
    }
    for (int c = t; c < C_; c += 512) {
        const float4* r4 = (const float4*)(X + (size_t)c * D_);
        xs_s[c] = pw96_sq_f4(r4) + pw96_sq_f4(r4 + 24);
        ids[c]  = 255;
    }
    __syncthreads();

    for (int iter = 0;; ++iter) {
        if (t < 4) {
            cs4[t] = pw96_sq_s(cent[t]) + pw96_sq_s(cent[t] + 96);
            cnt[t] = 0;
        }
        if (t == 0) changed = 0;
        __syncthreads();

        const float q0 = cs4[0], q1 = cs4[1], q2 = cs4[2], q3 = cs4[3];
        int lc0 = 0, lc1 = 0, lc2 = 0, lc3 = 0, mych = 0;
        for (int j = 0; j < 4; ++j) {
            const int c = t + 512 * j;
            const float4* r4 = (const float4*)(X + (size_t)c * D_);
            float d0 = 0.f, d1 = 0.f, d2 = 0.f, d3 = 0.f;
#pragma unroll 8
            for (int i = 0; i < 48; ++i) {
                const float4 a  = r4[i];
                const float4 c0 = *(const float4*)&cent[0][4 * i];
                const float4 c1 = *(const float4*)&cent[1][4 * i];
                const float4 c2 = *(const float4*)&cent[2][4 * i];
                const float4 c3 = *(const float4*)&cent[3][4 * i];
                d0 = fmaf(a.x, c0.x, d0); d0 = fmaf(a.y, c0.y, d0);
                d0 = fmaf(a.z, c0.z, d0); d0 = fmaf(a.w, c0.w, d0);
                d1 = fmaf(a.x, c1.x, d1); d1 = fmaf(a.y, c1.y, d1);
                d1 = fmaf(a.z, c1.z, d1); d1 = fmaf(a.w, c1.w, d1);
                d2 = fmaf(a.x, c2.x, d2); d2 = fmaf(a.y, c2.y, d2);
                d2 = fmaf(a.z, c2.z, d2); d2 = fmaf(a.w, c2.w, d2);
                d3 = fmaf(a.x, c3.x, d3); d3 = fmaf(a.y, c3.y, d3);
                d3 = fmaf(a.z, c3.z, d3); d3 = fmaf(a.w, c3.w, d3);
            }
            const float xv = xs_s[c];
            const float e0 = (xv - 2.0f * d0) + q0;
            const float e1 = (xv - 2.0f * d1) + q1;
            const float e2 = (xv - 2.0f * d2) + q2;
            const float e3 = (xv - 2.0f * d3) + q3;
            int id = 0; float best = e0;
            if (e1 < best) { best = e1; id = 1; }
            if (e2 < best) { best = e2; id = 2; }
            if (e3 < best) { best = e3; id = 3; }
            lc0 += (id == 0); lc1 += (id == 1); lc2 += (id == 2); lc3 += (id == 3);
            mych |= (ids[c] != (unsigned char)id);
            ids[c] = (unsigned char)id;
        }
#pragma unroll
        for (int off = 32; off > 0; off >>= 1) {
            lc0 += __shfl_down(lc0, off);
            lc1 += __shfl_down(lc1, off);
            lc2 += __shfl_down(lc2, off);
            lc3 += __shfl_down(lc3, off);
        }
        if (lane == 0) {
            atomicAdd(&cnt[0], lc0); atomicAdd(&cnt[1], lc1);
            atomicAdd(&cnt[2], lc2); atomicAdd(&cnt[3], lc3);
        }
        if (mych) changed = 1;
        __syncthreads();

        if (changed == 0 || iter == 10) break;

        if (t < 192) {
            float t0 = 0.f, t1 = 0.f, t2 = 0.f, t3 = 0.f;
            for (int kb = 0; kb < C_; kb += BLAS_Q) {
                const int ke = (kb + BLAS_Q < C_) ? (kb + BLAS_Q) : C_;
                float s0 = 0.f, s1 = 0.f, s2 = 0.f, s3 = 0.f;
                for (int c = kb; c < ke; ++c) {
                    const float xv = X[(size_t)c * D_ + t];
                    const int id = ids[c];
                    s0 += (id == 0) ? xv : 0.0f;
                    s1 += (id == 1) ? xv : 0.0f;
                    s2 += (id == 2) ? xv : 0.0f;
                    s3 += (id == 3) ? xv : 0.0f;
                }
                t0 += s0; t1 += s1; t2 += s2; t3 += s3;
            }
            if (cnt[0] > 0) cent[0][t] = t0 / (float)cnt[0];
            if (cnt[1] > 0) cent[1][t] = t1 / (float)cnt[1];
            if (cnt[2] > 0) cent[2][t] = t2 / (float)cnt[2];
            if (cnt[3] > 0) cent[3][t] = t3 / (float)cnt[3];
        }
        __syncthreads();
    }

    for (int c = t; c < C_; c += 512) ids_out[(size_t)b * C_ + c] = ids[c];
}

// ---------------------------------------------------------------------------
__device__ __forceinline__ float bn_apply(float v, float g, float be, float m, float va) {
    return (v - m) / sqrtf(va + EPSf) * g + be;
}

// ---------------------------------------------------------------------------
// Kernel 3: batched 64x64-tiled GEMM, M=256, N=512, K=2048.
// ---------------------------------------------------------------------------
__global__ __launch_bounds__(256) void gemm1_kernel(
    const float* __restrict__ pooled, const unsigned char* __restrict__ ids,
    const float* __restrict__ Wg, const float* __restrict__ bg,
    const float* __restrict__ g_gamma, const float* __restrict__ g_beta,
    const float* __restrict__ g_mean, const float* __restrict__ g_var,
    const float* __restrict__ gb_gamma, const float* __restrict__ gb_beta,
    const float* __restrict__ gb_mean, const float* __restrict__ gb_var,
    const float* __restrict__ W1, const float* __restrict__ b1,
    const float* __restrict__ n1_gamma, const float* __restrict__ n1_beta,
    const float* __restrict__ n1_mean, const float* __restrict__ n1_var,
    float* __restrict__ xg2, float* __restrict__ h1) {
    const int z = blockIdx.z;
    const int bn0 = blockIdx.x * 64, bm0 = blockIdx.y * 64;
    const float* Bmat = (z == 0) ? Wg : W1;
    __shared__ float As[32][68];
    __shared__ float Bs[32][68];
    float acc[4][4] = {};
    const int t = threadIdx.x;
    const int tx = t & 15, ty = t >> 4;

    for (int k0 = 0; k0 < 2048; k0 += 32) {
#pragma unroll
        for (int u = 0; u < 2; ++u) {
            const int idx = t + 256 * u;
            const int m = idx >> 3, kc = idx & 7;
            float4 v = *(const float4*)(pooled + (size_t)(bm0 + m) * 2048 + k0 + kc * 4);
            if (z > 0) {
                const unsigned int uu =
                    *(const unsigned int*)(ids + (size_t)(bm0 + m) * 2048 + k0 + kc * 4);
                const unsigned int k = (unsigned int)(z - 1);
                v.x = ((uu & 0xffu) == k) ? v.x : 0.f;
                v.y = (((uu >> 8) & 0xffu) == k) ? v.y : 0.f;
                v.z = (((uu >> 16) & 0xffu) == k) ? v.z : 0.f;
                v.w = (((uu >> 24) & 0xffu) == k) ? v.w : 0.f;
            }
            As[kc * 4 + 0][m] = v.x; As[kc * 4 + 1][m] = v.y;
            As[kc * 4 + 2][m] = v.z; As[kc * 4 + 3][m] = v.w;
            const float4 wv = *(const float4*)(Bmat + (size_t)(bn0 + m) * 2048 + k0 + kc * 4);
            Bs[kc * 4 + 0][m] = wv.x; Bs[kc * 4 + 1][m] = wv.y;
            Bs[kc * 4 + 2][m] = wv.z; Bs[kc * 4 + 3][m] = wv.w;
        }
        __syncthreads();
#pragma unroll 8
        for (int kk = 0; kk < 32; ++kk) {
            const float4 a = *(const float4*)&As[kk][ty * 4];
            const float4 wv = *(const float4*)&Bs[kk][tx * 4];
            const float av[4] = {a.x, a.y, a.z, a.w};
            const float bv[4] = {wv.x, wv.y, wv.z, wv.w};
#pragma unroll
            for (int i = 0; i < 4; ++i)
#pragma unroll
                for (int j = 0; j < 4; ++j) acc[i][j] += av[i] * bv[j];
        }
        __syncthreads();
    }

    const int m0 = bm0 + ty * 4, n0 = bn0 + tx * 4;
    if (z == 0) {
#pragma unroll
        for (int j = 0; j < 4; ++j) {
            const int n = n0 + j;
            const float bgv = bg[n];
            const float g1 = g_gamma[n], be1 = g_beta[n], mm1 = g_mean[n], vv1 = g_var[n];
            const float g2 = gb_gamma[n], be2 = gb_beta[n], mm2 = gb_mean[n], vv2 = gb_var[n];
#pragma unroll
            for (int i = 0; i < 4; ++i) {
                float v = acc[i][j] + bgv;
                v = bn_apply(v, g1, be1, mm1, vv1);
                v = fmaxf(v, 0.f);
                v = bn_apply(v, g2, be2, mm2, vv2);
                xg2[(size_t)(m0 + i) * 512 + n] = v;
            }
        }
    } else {
        const int k = z - 1;
#pragma unroll
        for (int j = 0; j < 4; ++j) {
            const int n = n0 + j;
            const float b1v = b1[n];
            const float g1 = n1_gamma[n], be1 = n1_beta[n], mm1 = n1_mean[n], vv1 = n1_var[n];
#pragma unroll
            for (int i = 0; i < 4; ++i) {
                float v = acc[i][j] + b1v;
                v = bn_apply(v, g1, be1, mm1, vv1);
                v = fmaxf(v, 0.f);
                h1[((size_t)k * 256 + (m0 + i)) * 512 + n] = v;
            }
        }
    }
}

// ---------------------------------------------------------------------------
// Kernel 4
// ---------------------------------------------------------------------------
__global__ __launch_bounds__(256) void gemm2_kernel(
    const float* __restrict__ h1, const float* __restrict__ W2,
    const float* __restrict__ b2,
    const float* __restrict__ n2_gamma, const float* __restrict__ n2_beta,
    const float* __restrict__ n2_mean, const float* __restrict__ n2_var,
    const float* __restrict__ bk_gamma, const float* __restrict__ bk_beta,
    const float* __restrict__ bk_mean, const float* __restrict__ bk_var,
    float* __restrict__ yv) {
    const int bn0 = blockIdx.x * 64, bm0 = blockIdx.y * 64;
    __shared__ float As[32][68];
    __shared__ float Bs[32][68];
    float acc[4][4] = {};
    const int t = threadIdx.x;
    const int tx = t & 15, ty = t >> 4;

    for (int k0 = 0; k0 < 512; k0 += 32) {
#pragma unroll
        for (int u = 0; u < 2; ++u) {
            const int idx = t + 256 * u;
            const int m = idx >> 3, kc = idx & 7;
            const float4 v = *(const float4*)(h1 + (size_t)(bm0 + m) * 512 + k0 + kc * 4);
            As[kc * 4 + 0][m] = v.x; As[kc * 4 + 1][m] = v.y;
            As[kc * 4 + 2][m] = v.z; As[kc * 4 + 3][m] = v.w;
            const float4 wv = *(const float4*)(W2 + (size_t)(bn0 + m) * 512 + k0 + kc * 4);
            Bs[kc * 4 + 0][m] = wv.x; Bs[kc * 4 + 1][m] = wv.y;
            Bs[kc * 4 + 2][m] = wv.z; Bs[kc * 4 + 3][m] = wv.w;
        }
        __syncthreads();
#pragma unroll 8
        for (int kk = 0; kk < 32; ++kk) {
            const float4 a = *(const float4*)&As[kk][ty * 4];
            const float4 wv = *(const float4*)&Bs[kk][tx * 4];
            const float av[4] = {a.x, a.y, a.z, a.w};
            const float bv[4] = {wv.x, wv.y, wv.z, wv.w};
#pragma unroll
            for (int i = 0; i < 4; ++i)
#pragma unroll
                for (int j = 0; j < 4; ++j) acc[i][j] += av[i] * bv[j];
        }
        __syncthreads();
    }

    const int m0 = bm0 + ty * 4, n0 = bn0 + tx * 4;
#pragma unroll
    for (int j = 0; j < 4; ++j) {
        const int n = n0 + j;
        const float b2v = b2[n];
        const float g1 = n2_gamma[n], be1 = n2_beta[n], mm1 = n2_mean[n], vv1 = n2_var[n];
#pragma unroll
        for (int i = 0; i < 4; ++i) {
            const int row = m0 + i;
            const int k = row >> 8, b = row & 255;
            float v = acc[i][j] + b2v;
            v = bn_apply(v, g1, be1, mm1, vv1);
            v = fmaxf(v, 0.f);
            const int pi = k * 128 + n;
            v = bn_apply(v, bk_gamma[pi], bk_beta[pi], bk_mean[pi], bk_var[pi]);
            yv[(size_t)b * 512 + pi] = v;
        }
    }
}

// ---------------------------------------------------------------------------
// Kernel 5: heads
// ---------------------------------------------------------------------------
__global__ __launch_bounds__(128) void head_kernel(
    const float* __restrict__ xg2, const float* __restrict__ yv,
    const float* __restrict__ Wcg, const float* __restrict__ bcg,
    const float* __restrict__ Wck, const float* __restrict__ bck,
    float* __restrict__ out) {
    const int b = blockIdx.x, t = threadIdx.x;
    __shared__ float xr[512], yr[512];
    ((float4*)xr)[t] = ((const float4*)(xg2 + (size_t)b * 512))[t];
    ((float4*)yr)[t] = ((const float4*)(yv + (size_t)b * 512))[t];
    __syncthreads();
    if (t < 51) {
        float acc = 0.f;
        const float4* wr = (const float4*)(Wcg + (size_t)t * 512);
        const float4* xv = (const float4*)xr;
#pragma unroll 8
        for (int p = 0; p < 128; ++p) {
            const float4 w4 = wr[p], v4 = xv[p];
            acc += w4.x * v4.x + w4.y * v4.y + w4.z * v4.z + w4.w * v4.w;
        }
        out[(size_t)b * 51 + t] = acc + bcg[t];
    } else if (t >= 64 && t < 115) {
        const int n = t - 64;
        float acc = 0.f;
        const float4* wr = (const float4*)(Wck + (size_t)n * 512);
        const float4* yv4 = (const float4*)yr;
#pragma unroll 8
        for (int p = 0; p < 128; ++p) {
            const float4 w4 = wr[p], v4 = yv4[p];
            acc += w4.x * v4.x + w4.y * v4.y + w4.z * v4.z + w4.w * v4.w;
        }
        out[(size_t)(B_ * 51) + (size_t)b * 51 + n] = acc + bck[n];
    }
}

// ---------------------------------------------------------------------------
extern "C" void kernel_launch(void* const* d_in, const int* in_sizes, int n_in,
                              void* d_out, int out_size, void* d_ws, size_t ws_size,
                              hipStream_t stream) {
    const float* x        = (const float*)d_in[0];
    const float* Wg       = (const float*)d_in[1];
    const float* bg       = (const float*)d_in[2];
    const float* g_gamma  = (const float*)d_in[3];
    const float* g_beta   = (const float*)d_in[4];
    const float* g_mean   = (const float*)d_in[5];
    const float* g_var    = (const float*)d_in[6];
    const float* gb_gamma = (const float*)d_in[7];
    const float* gb_beta  = (const float*)d_in[8];
    const float* gb_mean  = (const float*)d_in[9];
    const float* gb_var   = (const float*)d_in[10];
    const float* Wcg      = (const float*)d_in[11];
    const float* bcg      = (const float*)d_in[12];
    const float* W1       = (const float*)d_in[13];
    const float* b1       = (const float*)d_in[14];
    const float* n1_gamma = (const float*)d_in[15];
    const float* n1_beta  = (const float*)d_in[16];
    const float* n1_mean  = (const float*)d_in[17];
    const float* n1_var   = (const float*)d_in[18];
    const float* W2       = (const float*)d_in[19];
    const float* b2       = (const float*)d_in[20];
    const float* n2_gamma = (const float*)d_in[21];
    const float* n2_beta  = (const float*)d_in[22];
    const float* n2_mean  = (const float*)d_in[23];
    const float* n2_var   = (const float*)d_in[24];
    const float* bk_gamma = (const float*)d_in[25];
    const float* bk_beta  = (const float*)d_in[26];
    const float* bk_mean  = (const float*)d_in[27];
    const float* bk_var   = (const float*)d_in[28];
    const float* Wck      = (const float*)d_in[29];
    const float* bck      = (const float*)d_in[30];
    float* out = (float*)d_out;

    const size_t xt_elems    = (size_t)B_ * C_ * D_;              // 100,663,296 floats
    const size_t small_elems = 524288 * 2 + 131072 + 524288 + 131072; // pooled,xs,xg2,h1,yv
    const size_t need_fast   = xt_elems * 4 + small_elems * 4 + 524288 + 256;

    if (ws_size >= need_fast) {
        float* xT          = (float*)d_ws;
        float* pooled      = xT + xt_elems;                      // 524288 f
        float* xs_g        = pooled + 524288;                    // 524288 f
        unsigned char* ids = (unsigned char*)(xs_g + 524288);    // 524288 B
        float* xg2         = (float*)(ids + 524288);             // 131072 f
        float* h1          = xg2 + 131072;                       // 524288 f
        float* yv          = h1 + 524288;                        // 131072 f

        transpose_kernel<<<dim3(32, B_), dim3(256), 0, stream>>>(x, xT, pooled, xs_g);
        kmeans_fast_kernel<<<dim3(B_), dim3(1024), 0, stream>>>(x, xT, xs_g, ids);
        gemm1_kernel<<<dim3(8, 4, 5), dim3(256), 0, stream>>>(
            pooled, ids, Wg, bg, g_gamma, g_beta, g_mean, g_var,
            gb_gamma, gb_beta, gb_mean, gb_var, W1, b1,
            n1_gamma, n1_beta, n1_mean, n1_var, xg2, h1);
        gemm2_kernel<<<dim3(2, 16), dim3(256), 0, stream>>>(
            h1, W2, b2, n2_gamma, n2_beta, n2_mean, n2_var,
            bk_gamma, bk_beta, bk_mean, bk_var, yv);
        head_kernel<<<dim3(B_), dim3(128), 0, stream>>>(xg2, yv, Wcg, bcg, Wck, bck, out);
    } else {
        float* pooled      = (float*)d_ws;                       // 524288 f
        unsigned char* ids = (unsigned char*)(pooled + 524288);  // 524288 B
        float* xg2         = (float*)(ids + 524288);             // 131072 f
        float* h1          = xg2 + 131072;                       // 524288 f
        float* yv          = h1 + 524288;                        // 131072 f

        pool_kernel<<<dim3((B_ * C_) / 4), dim3(256), 0, stream>>>(x, pooled);
        kmeans_fb_kernel<<<dim3(B_), dim3(512), 0, stream>>>(x, ids);
        gemm1_kernel<<<dim3(8, 4, 5), dim3(256), 0, stream>>>(
            pooled, ids, Wg, bg, g_gamma, g_beta, g_mean, g_var,
            gb_gamma, gb_beta, gb_mean, gb_var, W1, b1,
            n1_gamma, n1_beta, n1_mean, n1_var, xg2, h1);
        gemm2_kernel<<<dim3(2, 16), dim3(256), 0, stream>>>(
            h1, W2, b2, n2_gamma, n2_beta, n2_mean, n2_var,
            bk_gamma, bk_beta, bk_mean, bk_var, yv);
        head_kernel<<<dim3(B_), dim3(128), 0, stream>>>(xg2, yv, Wcg, bcg, Wck, bck, out);
    }
}

// Round 15
// 1743.761 us; speedup vs baseline: 1.0320x; 1.0028x over previous
//
#include <hip/hip_runtime.h>
#include <math.h>

#define B_   256
#define C_   2048
#define D_   192
#define EPSf 1e-5f
#define BLAS_Q 384   // OpenBLAS SGEMM_DEFAULT_Q — K-block size (validated in R5)

// ---------------------------------------------------------------------------
// numpy pairwise helpers (validated bit-exact in R5/R8/R10/R11/R13/R14).
// ---------------------------------------------------------------------------
__device__ __forceinline__ float pw96_sq_f4(const float4* a4) {
    float r0 = 0.f, r1 = 0.f, r2 = 0.f, r3 = 0.f, r4 = 0.f, r5 = 0.f, r6 = 0.f, r7 = 0.f;
#pragma unroll
    for (int i = 0; i < 12; ++i) {
        const float4 v0 = a4[2 * i], v1 = a4[2 * i + 1];
        r0 += __fmul_rn(v0.x, v0.x); r1 += __fmul_rn(v0.y, v0.y);
        r2 += __fmul_rn(v0.z, v0.z); r3 += __fmul_rn(v0.w, v0.w);
        r4 += __fmul_rn(v1.x, v1.x); r5 += __fmul_rn(v1.y, v1.y);
        r6 += __fmul_rn(v1.z, v1.z); r7 += __fmul_rn(v1.w, v1.w);
    }
    return ((r0 + r1) + (r2 + r3)) + ((r4 + r5) + (r6 + r7));
}

__device__ __forceinline__ float pw96_sq_s(const float* a) {
    float r0 = 0.f, r1 = 0.f, r2 = 0.f, r3 = 0.f, r4 = 0.f, r5 = 0.f, r6 = 0.f, r7 = 0.f;
#pragma unroll
    for (int i = 0; i < 12; ++i) {
        r0 += __fmul_rn(a[8 * i + 0], a[8 * i + 0]);
        r1 += __fmul_rn(a[8 * i + 1], a[8 * i + 1]);
        r2 += __fmul_rn(a[8 * i + 2], a[8 * i + 2]);
        r3 += __fmul_rn(a[8 * i + 3], a[8 * i + 3]);
        r4 += __fmul_rn(a[8 * i + 4], a[8 * i + 4]);
        r5 += __fmul_rn(a[8 * i + 5], a[8 * i + 5]);
        r6 += __fmul_rn(a[8 * i + 6], a[8 * i + 6]);
        r7 += __fmul_rn(a[8 * i + 7], a[8 * i + 7]);
    }
    return ((r0 + r1) + (r2 + r3)) + ((r4 + r5) + (r6 + r7));
}

__device__ __forceinline__ float pw96_sum_s(const float* a) {
    float r0 = 0.f, r1 = 0.f, r2 = 0.f, r3 = 0.f, r4 = 0.f, r5 = 0.f, r6 = 0.f, r7 = 0.f;
#pragma unroll
    for (int i = 0; i < 12; ++i) {
        r0 += a[8 * i + 0]; r1 += a[8 * i + 1];
        r2 += a[8 * i + 2]; r3 += a[8 * i + 3];
        r4 += a[8 * i + 4]; r5 += a[8 * i + 5];
        r6 += a[8 * i + 6]; r7 += a[8 * i + 7];
    }
    return ((r0 + r1) + (r2 + r3)) + ((r4 + r5) + (r6 + r7));
}

// ---------------------------------------------------------------------------
// Kernel 0 (fast path): fused transpose + xs + pooled (validated R14).
// ---------------------------------------------------------------------------
__global__ __launch_bounds__(256) void transpose_kernel(const float* __restrict__ x,
                                                        float* __restrict__ xT,
                                                        float* __restrict__ pooled,
                                                        float* __restrict__ xs_g) {
    const int c0 = blockIdx.x * 64, b = blockIdx.y;
    const float* X = x + (size_t)b * (C_ * (size_t)D_);
    float* XT      = xT + (size_t)b * (C_ * (size_t)D_);
    __shared__ float lds[64 * 193];
    const int t = threadIdx.x;

#pragma unroll
    for (int i = 0; i < 12; ++i) {
        const int idx = i * 256 + t;
        const int r = idx / 48, j = idx % 48;
        const float4 v = *(const float4*)(X + (size_t)(c0 + r) * D_ + 4 * j);
        float* p = &lds[r * 193 + 4 * j];
        p[0] = v.x; p[1] = v.y; p[2] = v.z; p[3] = v.w;
    }
    __syncthreads();

    if (t < 64) {
        const float* row = &lds[t * 193];
        xs_g[(size_t)b * C_ + c0 + t]   = pw96_sq_s(row)  + pw96_sq_s(row + 96);
        pooled[(size_t)b * C_ + c0 + t] = (pw96_sum_s(row) + pw96_sum_s(row + 96)) / 192.0f;
    }

#pragma unroll
    for (int i = 0; i < 48; ++i) {
        const int idx = i * 256 + t;
        const int d = idx >> 6, ch = idx & 63;
        XT[(size_t)d * C_ + c0 + ch] = lds[ch * 193 + d];
    }
}

// ---------------------------------------------------------------------------
// Batch-16 compute helpers (float2; FP chain order per channel == R14 PASS)
// ---------------------------------------------------------------------------
__device__ __forceinline__ void pa_comp16_f2(const float2 (&vb)[16], int dbase,
                                             const float (*cent)[192],
                                             float (&acc)[2][4]) {
#pragma unroll
    for (int u = 0; u < 16; ++u) {
        const int d = dbase + u;
        const float c0 = cent[0][d], c1 = cent[1][d];
        const float c2 = cent[2][d], c3 = cent[3][d];
        acc[0][0] = fmaf(vb[u].x, c0, acc[0][0]);
        acc[1][0] = fmaf(vb[u].y, c0, acc[1][0]);
        acc[0][1] = fmaf(vb[u].x, c1, acc[0][1]);
        acc[1][1] = fmaf(vb[u].y, c1, acc[1][1]);
        acc[0][2] = fmaf(vb[u].x, c2, acc[0][2]);
        acc[1][2] = fmaf(vb[u].y, c2, acc[1][2]);
        acc[0][3] = fmaf(vb[u].x, c3, acc[0][3]);
        acc[1][3] = fmaf(vb[u].y, c3, acc[1][3]);
    }
}

__device__ __forceinline__ void pb_comp16_f2(const float2 (&vb)[16], int cbase,
                                             const unsigned char* ids,
                                             float (&s)[2][4]) {
#pragma unroll
    for (int u = 0; u < 16; ++u) {
        const int id = ids[cbase + u];
        s[0][0] += (id == 0) ? vb[u].x : 0.0f;
        s[1][0] += (id == 0) ? vb[u].y : 0.0f;
        s[0][1] += (id == 1) ? vb[u].x : 0.0f;
        s[1][1] += (id == 1) ? vb[u].y : 0.0f;
        s[0][2] += (id == 2) ? vb[u].x : 0.0f;
        s[1][2] += (id == 2) ? vb[u].y : 0.0f;
        s[0][3] += (id == 3) ? vb[u].x : 0.0f;
        s[1][3] += (id == 3) ? vb[u].y : 0.0f;
    }
}

// ---------------------------------------------------------------------------
// Kernel 1 (fast path): kmeans, 1024 thr/block (16 waves/CU), 1 block/sample.
// R15 CHANGE vs R14: batch-16 (16 loads issued back-to-back, then 16
// computes) in Phase A and Phase B -> 128 KB/CU in flight (2x R14).
// Consume order per channel/dim chain UNCHANGED -> bit-identical to R14 PASS.
// ---------------------------------------------------------------------------
__global__ __launch_bounds__(1024) void kmeans_fast_kernel(const float* __restrict__ x,
                                                           const float* __restrict__ xT,
                                                           const float* __restrict__ xs_g,
                                                           unsigned char* __restrict__ ids_out) {
    const int b = blockIdx.x, t = threadIdx.x;
    const int lane = t & 63;
    const float* X   = x  + (size_t)b * (C_ * (size_t)D_);
    const float* XTb = xT + (size_t)b * (C_ * (size_t)D_);

    __shared__ __align__(16) float cent[4][192];
    __shared__ float xs_s[C_];
    __shared__ float part[6][4][192];
    __shared__ float cs4[4];
    __shared__ int   cnt[4];
    __shared__ int   changed;
    __shared__ unsigned char ids[C_];

    if (t < 192) {
        cent[0][t] = X[(size_t)0    * D_ + t];
        cent[1][t] = X[(size_t)512  * D_ + t];
        cent[2][t] = X[(size_t)1024 * D_ + t];
        cent[3][t] = X[(size_t)1536 * D_ + t];
    }
    {
        const int c2 = 2 * t;
        const float2 xv2 = *(const float2*)(xs_g + (size_t)b * C_ + c2);
        xs_s[c2] = xv2.x; xs_s[c2 + 1] = xv2.y;
        ids[c2] = 255; ids[c2 + 1] = 255;
    }
    __syncthreads();

    for (int iter = 0;; ++iter) {
        if (t < 4) {
            cs4[t] = pw96_sq_s(cent[t]) + pw96_sq_s(cent[t] + 96);
            cnt[t] = 0;
        }
        if (t == 0) changed = 0;
        __syncthreads();

        const float q0 = cs4[0], q1 = cs4[1], q2 = cs4[2], q3 = cs4[3];

        // ---- Phase A: channels 2t, 2t+1; batch-16 float2 loads ----
        int lc0 = 0, lc1 = 0, lc2 = 0, lc3 = 0, mych = 0;
        {
            const float2* pA = (const float2*)XTb + t;   // stride per d = 1024 f2
            float acc[2][4] = {};
            float2 buf[16];
            for (int db = 0; db < 192; db += 16) {
#pragma unroll
                for (int u = 0; u < 16; ++u) buf[u] = pA[(size_t)(db + u) << 10];
                pa_comp16_f2(buf, db, cent, acc);
            }
#pragma unroll
            for (int ch = 0; ch < 2; ++ch) {
                const int c = 2 * t + ch;
                const float xv = xs_s[c];
                const float e0 = (xv - 2.0f * acc[ch][0]) + q0;
                const float e1 = (xv - 2.0f * acc[ch][1]) + q1;
                const float e2 = (xv - 2.0f * acc[ch][2]) + q2;
                const float e3 = (xv - 2.0f * acc[ch][3]) + q3;
                int id = 0; float best = e0;
                if (e1 < best) { best = e1; id = 1; }
                if (e2 < best) { best = e2; id = 2; }
                if (e3 < best) { best = e3; id = 3; }
                lc0 += (id == 0); lc1 += (id == 1); lc2 += (id == 2); lc3 += (id == 3);
                mych |= (ids[c] != (unsigned char)id);
                ids[c] = (unsigned char)id;
            }
        }
#pragma unroll
        for (int off = 32; off > 0; off >>= 1) {
            lc0 += __shfl_down(lc0, off);
            lc1 += __shfl_down(lc1, off);
            lc2 += __shfl_down(lc2, off);
            lc3 += __shfl_down(lc3, off);
        }
        if (lane == 0) {
            atomicAdd(&cnt[0], lc0); atomicAdd(&cnt[1], lc1);
            atomicAdd(&cnt[2], lc2); atomicAdd(&cnt[3], lc3);
        }
        if (mych) changed = 1;
        __syncthreads();

        if (changed == 0 || iter == 10) break;   // converged -> exact fixed point

        // ---- Phase B: 576 tasks (kb, dim-pair); batch-16 float2;
        // per-(dim,k) chains ascend c within clamped Q=384 blocks. ----
        if (t < 576) {
            const int kb = t / 96;
            const int dg = t - kb * 96;           // dims 2dg, 2dg+1
            const int cb = kb * BLAS_Q;
            const int ce = (cb + BLAS_Q < C_) ? (cb + BLAS_Q) : C_;
            const int nc = ce - cb;               // 384 or 128 (both /16)
            const float2* pB = (const float2*)X + (size_t)cb * 96 + dg;
            float s[2][4] = {};
            float2 buf[16];
            for (int c0i = 0; c0i < nc; c0i += 16) {
#pragma unroll
                for (int u = 0; u < 16; ++u) buf[u] = pB[(size_t)(c0i + u) * 96];
                pb_comp16_f2(buf, cb + c0i, ids, s);
            }
#pragma unroll
            for (int k = 0; k < 4; ++k) {
                part[kb][k][2 * dg + 0] = s[0][k];
                part[kb][k][2 * dg + 1] = s[1][k];
            }
        }
        __syncthreads();
        if (t < 192) {
#pragma unroll
            for (int k = 0; k < 4; ++k) {
                float tt = part[0][k][t];          // = 0 + p0 exactly (R5 order)
                tt += part[1][k][t];
                tt += part[2][k][t];
                tt += part[3][k][t];
                tt += part[4][k][t];
                tt += part[5][k][t];
                if (cnt[k] > 0) cent[k][t] = tt / (float)cnt[k];
            }
        }
        __syncthreads();
    }

    *(uchar2*)(ids_out + (size_t)b * C_ + 2 * t) = *(uchar2*)&ids[2 * t];
}

// ---------------------------------------------------------------------------
// FALLBACK (ws too small): exact R8 PASS kernels.
// ---------------------------------------------------------------------------
__global__ __launch_bounds__(256) void pool_kernel(const float* __restrict__ x,
                                                   float* __restrict__ pooled) {
    const int row  = blockIdx.x * 4 + (threadIdx.x >> 6);
    const int lane = threadIdx.x & 63;
    const float* r = x + (size_t)row * D_;
    float s = 0.f;
    if (lane < 48) {
        const float4 v = ((const float4*)r)[lane];
        s = v.x + v.y + v.z + v.w;
    }
#pragma unroll
    for (int off = 32; off > 0; off >>= 1) s += __shfl_down(s, off);
    if (lane == 0) pooled[row] = s * (1.f / 192.f);
}

__global__ __launch_bounds__(512) void kmeans_fb_kernel(const float* __restrict__ x,
                                                        unsigned char* __restrict__ ids_out) {
    const int b = blockIdx.x, t = threadIdx.x;
    const int lane = t & 63;
    const float* X = x + (size_t)b * (C_ * (size_t)D_);

    __shared__ __align__(16) float cent[4][192];
    __shared__ float xs_s[C_];
    __shared__ float cs4[4];
    __shared__ int   cnt[4];
    __shared__ int   changed;
    __shared__ unsigned char ids[C_];

    if (t < 192) {
        cent[0][t] = X[(size_t)0    * D_ + t];
        cent[1][t] = X[(size_t)512  * D_ + t];
        cent[2][t] = X[(size_t)1024 * D_ + t];
        cent[3][t] = X[(size_t)1536 * D_ + t];
    }
    for (int c = t; c < C_; c += 512) {
        const float4* r4 = (const float4*)(X + (size_t)c * D_);
        xs_s[c] = pw96_sq_f4(r4) + pw96_sq_f4(r4 + 24);
        ids[c]  = 255;
    }
    __syncthreads();

    for (int iter = 0;; ++iter) {
        if (t < 4) {
            cs4[t] = pw96_sq_s(cent[t]) + pw96_sq_s(cent[t] + 96);
            cnt[t] = 0;
        }
        if (t == 0) changed = 0;
        __syncthreads();

        const float q0 = cs4[0], q1 = cs4[1], q2 = cs4[2], q3 = cs4[3];
        int lc0 = 0, lc1 = 0, lc2 = 0, lc3 = 0, mych = 0;
        for (int j = 0; j < 4; ++j) {
            const int c = t + 512 * j;
            const float4* r4 = (const float4*)(X + (size_t)c * D_);
            float d0 = 0.f, d1 = 0.f, d2 = 0.f, d3 = 0.f;
#pragma unroll 8
            for (int i = 0; i < 48; ++i) {
                const float4 a  = r4[i];
                const float4 c0 = *(const float4*)&cent[0][4 * i];
                const float4 c1 = *(const float4*)&cent[1][4 * i];
                const float4 c2 = *(const float4*)&cent[2][4 * i];
                const float4 c3 = *(const float4*)&cent[3][4 * i];
                d0 = fmaf(a.x, c0.x, d0); d0 = fmaf(a.y, c0.y, d0);
                d0 = fmaf(a.z, c0.z, d0); d0 = fmaf(a.w, c0.w, d0);
                d1 = fmaf(a.x, c1.x, d1); d1 = fmaf(a.y, c1.y, d1);
                d1 = fmaf(a.z, c1.z, d1); d1 = fmaf(a.w, c1.w, d1);
                d2 = fmaf(a.x, c2.x, d2); d2 = fmaf(a.y, c2.y, d2);
                d2 = fmaf(a.z, c2.z, d2); d2 = fmaf(a.w, c2.w, d2);
                d3 = fmaf(a.x, c3.x, d3); d3 = fmaf(a.y, c3.y, d3);
                d3 = fmaf(a.z, c3.z, d3); d3 = fmaf(a.w, c3.w, d3);
            }
            const float xv = xs_s[c];
            const float e0 = (xv - 2.0f * d0) + q0;
            const float e1 = (xv - 2.0f * d1) + q1;
            const float e2 = (xv - 2.0f * d2) + q2;
            const float e3 = (xv - 2.0f * d3) + q3;
            int id = 0; float best = e0;
            if (e1 < best) { best = e1; id = 1; }
            if (e2 < best) { best = e2; id = 2; }
            if (e3 < best) { best = e3; id = 3; }
            lc0 += (id == 0); lc1 += (id == 1); lc2 += (id == 2); lc3 += (id == 3);
            mych |= (ids[c] != (unsigned char)id);
            ids[c] = (unsigned char)id;
        }
#pragma unroll
        for (int off = 32; off > 0; off >>= 1) {
            lc0 += __shfl_down(lc0, off);
            lc1 += __shfl_down(lc1, off);
            lc2 += __shfl_down(lc2, off);
            lc3 += __shfl_down(lc3, off);
        }
        if (lane == 0) {
            atomicAdd(&cnt[0], lc0); atomicAdd(&cnt[1], lc1);
            atomicAdd(&cnt[2], lc2); atomicAdd(&cnt[3], lc3);
        }
        if (mych) changed = 1;
        __syncthreads();

        if (changed == 0 || iter == 10) break;

        if (t < 192) {
            float t0 = 0.f, t1 = 0.f, t2 = 0.f, t3 = 0.f;
            for (int kb = 0; kb < C_; kb += BLAS_Q) {
                const int ke = (kb + BLAS_Q < C_) ? (kb + BLAS_Q) : C_;
                float s0 = 0.f, s1 = 0.f, s2 = 0.f, s3 = 0.f;
                for (int c = kb; c < ke; ++c) {
                    const float xv = X[(size_t)c * D_ + t];
                    const int id = ids[c];
                    s0 += (id == 0) ? xv : 0.0f;
                    s1 += (id == 1) ? xv : 0.0f;
                    s2 += (id == 2) ? xv : 0.0f;
                    s3 += (id == 3) ? xv : 0.0f;
                }
                t0 += s0; t1 += s1; t2 += s2; t3 += s3;
            }
            if (cnt[0] > 0) cent[0][t] = t0 / (float)cnt[0];
            if (cnt[1] > 0) cent[1][t] = t1 / (float)cnt[1];
            if (cnt[2] > 0) cent[2][t] = t2 / (float)cnt[2];
            if (cnt[3] > 0) cent[3][t] = t3 / (float)cnt[3];
        }
        __syncthreads();
    }

    for (int c = t; c < C_; c += 512) ids_out[(size_t)b * C_ + c] = ids[c];
}

// ---------------------------------------------------------------------------
__device__ __forceinline__ float bn_apply(float v, float g, float be, float m, float va) {
    return (v - m) / sqrtf(va + EPSf) * g + be;
}

// ---------------------------------------------------------------------------
// Kernel 3: batched 64x64-tiled GEMM, M=256, N=512, K=2048.
// ---------------------------------------------------------------------------
__global__ __launch_bounds__(256) void gemm1_kernel(
    const float* __restrict__ pooled, const unsigned char* __restrict__ ids,
    const float* __restrict__ Wg, const float* __restrict__ bg,
    const float* __restrict__ g_gamma, const float* __restrict__ g_beta,
    const float* __restrict__ g_mean, const float* __restrict__ g_var,
    const float* __restrict__ gb_gamma, const float* __restrict__ gb_beta,
    const float* __restrict__ gb_mean, const float* __restrict__ gb_var,
    const float* __restrict__ W1, const float* __restrict__ b1,
    const float* __restrict__ n1_gamma, const float* __restrict__ n1_beta,
    const float* __restrict__ n1_mean, const float* __restrict__ n1_var,
    float* __restrict__ xg2, float* __restrict__ h1) {
    const int z = blockIdx.z;
    const int bn0 = blockIdx.x * 64, bm0 = blockIdx.y * 64;
    const float* Bmat = (z == 0) ? Wg : W1;
    __shared__ float As[32][68];
    __shared__ float Bs[32][68];
    float acc[4][4] = {};
    const int t = threadIdx.x;
    const int tx = t & 15, ty = t >> 4;

    for (int k0 = 0; k0 < 2048; k0 += 32) {
#pragma unroll
        for (int u = 0; u < 2; ++u) {
            const int idx = t + 256 * u;
            const int m = idx >> 3, kc = idx & 7;
            float4 v = *(const float4*)(pooled + (size_t)(bm0 + m) * 2048 + k0 + kc * 4);
            if (z > 0) {
                const unsigned int uu =
                    *(const unsigned int*)(ids + (size_t)(bm0 + m) * 2048 + k0 + kc * 4);
                const unsigned int k = (unsigned int)(z - 1);
                v.x = ((uu & 0xffu) == k) ? v.x : 0.f;
                v.y = (((uu >> 8) & 0xffu) == k) ? v.y : 0.f;
                v.z = (((uu >> 16) & 0xffu) == k) ? v.z : 0.f;
                v.w = (((uu >> 24) & 0xffu) == k) ? v.w : 0.f;
            }
            As[kc * 4 + 0][m] = v.x; As[kc * 4 + 1][m] = v.y;
            As[kc * 4 + 2][m] = v.z; As[kc * 4 + 3][m] = v.w;
            const float4 wv = *(const float4*)(Bmat + (size_t)(bn0 + m) * 2048 + k0 + kc * 4);
            Bs[kc * 4 + 0][m] = wv.x; Bs[kc * 4 + 1][m] = wv.y;
            Bs[kc * 4 + 2][m] = wv.z; Bs[kc * 4 + 3][m] = wv.w;
        }
        __syncthreads();
#pragma unroll 8
        for (int kk = 0; kk < 32; ++kk) {
            const float4 a = *(const float4*)&As[kk][ty * 4];
            const float4 wv = *(const float4*)&Bs[kk][tx * 4];
            const float av[4] = {a.x, a.y, a.z, a.w};
            const float bv[4] = {wv.x, wv.y, wv.z, wv.w};
#pragma unroll
            for (int i = 0; i < 4; ++i)
#pragma unroll
                for (int j = 0; j < 4; ++j) acc[i][j] += av[i] * bv[j];
        }
        __syncthreads();
    }

    const int m0 = bm0 + ty * 4, n0 = bn0 + tx * 4;
    if (z == 0) {
#pragma unroll
        for (int j = 0; j < 4; ++j) {
            const int n = n0 + j;
            const float bgv = bg[n];
            const float g1 = g_gamma[n], be1 = g_beta[n], mm1 = g_mean[n], vv1 = g_var[n];
            const float g2 = gb_gamma[n], be2 = gb_beta[n], mm2 = gb_mean[n], vv2 = gb_var[n];
#pragma unroll
            for (int i = 0; i < 4; ++i) {
                float v = acc[i][j] + bgv;
                v = bn_apply(v, g1, be1, mm1, vv1);
                v = fmaxf(v, 0.f);
                v = bn_apply(v, g2, be2, mm2, vv2);
                xg2[(size_t)(m0 + i) * 512 + n] = v;
            }
        }
    } else {
        const int k = z - 1;
#pragma unroll
        for (int j = 0; j < 4; ++j) {
            const int n = n0 + j;
            const float b1v = b1[n];
            const float g1 = n1_gamma[n], be1 = n1_beta[n], mm1 = n1_mean[n], vv1 = n1_var[n];
#pragma unroll
            for (int i = 0; i < 4; ++i) {
                float v = acc[i][j] + b1v;
                v = bn_apply(v, g1, be1, mm1, vv1);
                v = fmaxf(v, 0.f);
                h1[((size_t)k * 256 + (m0 + i)) * 512 + n] = v;
            }
        }
    }
}

// ---------------------------------------------------------------------------
// Kernel 4
// ---------------------------------------------------------------------------
__global__ __launch_bounds__(256) void gemm2_kernel(
    const float* __restrict__ h1, const float* __restrict__ W2,
    const float* __restrict__ b2,
    const float* __restrict__ n2_gamma, const float* __restrict__ n2_beta,
    const float* __restrict__ n2_mean, const float* __restrict__ n2_var,
    const float* __restrict__ bk_gamma, const float* __restrict__ bk_beta,
    const float* __restrict__ bk_mean, const float* __restrict__ bk_var,
    float* __restrict__ yv) {
    const int bn0 = blockIdx.x * 64, bm0 = blockIdx.y * 64;
    __shared__ float As[32][68];
    __shared__ float Bs[32][68];
    float acc[4][4] = {};
    const int t = threadIdx.x;
    const int tx = t & 15, ty = t >> 4;

    for (int k0 = 0; k0 < 512; k0 += 32) {
#pragma unroll
        for (int u = 0; u < 2; ++u) {
            const int idx = t + 256 * u;
            const int m = idx >> 3, kc = idx & 7;
            const float4 v = *(const float4*)(h1 + (size_t)(bm0 + m) * 512 + k0 + kc * 4);
            As[kc * 4 + 0][m] = v.x; As[kc * 4 + 1][m] = v.y;
            As[kc * 4 + 2][m] = v.z; As[kc * 4 + 3][m] = v.w;
            const float4 wv = *(const float4*)(W2 + (size_t)(bn0 + m) * 512 + k0 + kc * 4);
            Bs[kc * 4 + 0][m] = wv.x; Bs[kc * 4 + 1][m] = wv.y;
            Bs[kc * 4 + 2][m] = wv.z; Bs[kc * 4 + 3][m] = wv.w;
        }
        __syncthreads();
#pragma unroll 8
        for (int kk = 0; kk < 32; ++kk) {
            const float4 a = *(const float4*)&As[kk][ty * 4];
            const float4 wv = *(const float4*)&Bs[kk][tx * 4];
            const float av[4] = {a.x, a.y, a.z, a.w};
            const float bv[4] = {wv.x, wv.y, wv.z, wv.w};
#pragma unroll
            for (int i = 0; i < 4; ++i)
#pragma unroll
                for (int j = 0; j < 4; ++j) acc[i][j] += av[i] * bv[j];
        }
        __syncthreads();
    }

    const int m0 = bm0 + ty * 4, n0 = bn0 + tx * 4;
#pragma unroll
    for (int j = 0; j < 4; ++j) {
        const int n = n0 + j;
        const float b2v = b2[n];
        const float g1 = n2_gamma[n], be1 = n2_beta[n], mm1 = n2_mean[n], vv1 = n2_var[n];
#pragma unroll
        for (int i = 0; i < 4; ++i) {
            const int row = m0 + i;
            const int k = row >> 8, b = row & 255;
            float v = acc[i][j] + b2v;
            v = bn_apply(v, g1, be1, mm1, vv1);
            v = fmaxf(v, 0.f);
            const int pi = k * 128 + n;
            v = bn_apply(v, bk_gamma[pi], bk_beta[pi], bk_mean[pi], bk_var[pi]);
            yv[(size_t)b * 512 + pi] = v;
        }
    }
}

// ---------------------------------------------------------------------------
// Kernel 5: heads
// ---------------------------------------------------------------------------
__global__ __launch_bounds__(128) void head_kernel(
    const float* __restrict__ xg2, const float* __restrict__ yv,
    const float* __restrict__ Wcg, const float* __restrict__ bcg,
    const float* __restrict__ Wck, const float* __restrict__ bck,
    float* __restrict__ out) {
    const int b = blockIdx.x, t = threadIdx.x;
    __shared__ float xr[512], yr[512];
    ((float4*)xr)[t] = ((const float4*)(xg2 + (size_t)b * 512))[t];
    ((float4*)yr)[t] = ((const float4*)(yv + (size_t)b * 512))[t];
    __syncthreads();
    if (t < 51) {
        float acc = 0.f;
        const float4* wr = (const float4*)(Wcg + (size_t)t * 512);
        const float4* xv = (const float4*)xr;
#pragma unroll 8
        for (int p = 0; p < 128; ++p) {
            const float4 w4 = wr[p], v4 = xv[p];
            acc += w4.x * v4.x + w4.y * v4.y + w4.z * v4.z + w4.w * v4.w;
        }
        out[(size_t)b * 51 + t] = acc + bcg[t];
    } else if (t >= 64 && t < 115) {
        const int n = t - 64;
        float acc = 0.f;
        const float4* wr = (const float4*)(Wck + (size_t)n * 512);
        const float4* yv4 = (const float4*)yr;
#pragma unroll 8
        for (int p = 0; p < 128; ++p) {
            const float4 w4 = wr[p], v4 = yv4[p];
            acc += w4.x * v4.x + w4.y * v4.y + w4.z * v4.z + w4.w * v4.w;
        }
        out[(size_t)(B_ * 51) + (size_t)b * 51 + n] = acc + bck[n];
    }
}

// ---------------------------------------------------------------------------
extern "C" void kernel_launch(void* const* d_in, const int* in_sizes, int n_in,
                              void* d_out, int out_size, void* d_ws, size_t ws_size,
                              hipStream_t stream) {
    const float* x        = (const float*)d_in[0];
    const float* Wg       = (const float*)d_in[1];
    const float* bg       = (const float*)d_in[2];
    const float* g_gamma  = (const float*)d_in[3];
    const float* g_beta   = (const float*)d_in[4];
    const float* g_mean   = (const float*)d_in[5];
    const float* g_var    = (const float*)d_in[6];
    const float* gb_gamma = (const float*)d_in[7];
    const float* gb_beta  = (const float*)d_in[8];
    const float* gb_mean  = (const float*)d_in[9];
    const float* gb_var   = (const float*)d_in[10];
    const float* Wcg      = (const float*)d_in[11];
    const float* bcg      = (const float*)d_in[12];
    const float* W1       = (const float*)d_in[13];
    const float* b1       = (const float*)d_in[14];
    const float* n1_gamma = (const float*)d_in[15];
    const float* n1_beta  = (const float*)d_in[16];
    const float* n1_mean  = (const float*)d_in[17];
    const float* n1_var   = (const float*)d_in[18];
    const float* W2       = (const float*)d_in[19];
    const float* b2       = (const float*)d_in[20];
    const float* n2_gamma = (const float*)d_in[21];
    const float* n2_beta  = (const float*)d_in[22];
    const float* n2_mean  = (const float*)d_in[23];
    const float* n2_var   = (const float*)d_in[24];
    const float* bk_gamma = (const float*)d_in[25];
    const float* bk_beta  = (const float*)d_in[26];
    const float* bk_mean  = (const float*)d_in[27];
    const float* bk_var   = (const float*)d_in[28];
    const float* Wck      = (const float*)d_in[29];
    const float* bck      = (const float*)d_in[30];
    float* out = (float*)d_out;

    const size_t xt_elems    = (size_t)B_ * C_ * D_;              // 100,663,296 floats
    const size_t small_elems = 524288 * 2 + 131072 + 524288 + 131072; // pooled,xs,xg2,h1,yv
    const size_t need_fast   = xt_elems * 4 + small_elems * 4 + 524288 + 256;

    if (ws_size >= need_fast) {
        float* xT          = (float*)d_ws;
        float* pooled      = xT + xt_elems;                      // 524288 f
        float* xs_g        = pooled + 524288;                    // 524288 f
        unsigned char* ids = (unsigned char*)(xs_g + 524288);    // 524288 B
        float* xg2         = (float*)(ids + 524288);             // 131072 f
        float* h1          = xg2 + 131072;                       // 524288 f
        float* yv          = h1 + 524288;                        // 131072 f

        transpose_kernel<<<dim3(32, B_), dim3(256), 0, stream>>>(x, xT, pooled, xs_g);
        kmeans_fast_kernel<<<dim3(B_), dim3(1024), 0, stream>>>(x, xT, xs_g, ids);
        gemm1_kernel<<<dim3(8, 4, 5), dim3(256), 0, stream>>>(
            pooled, ids, Wg, bg, g_gamma, g_beta, g_mean, g_var,
            gb_gamma, gb_beta, gb_mean, gb_var, W1, b1,
            n1_gamma, n1_beta, n1_mean, n1_var, xg2, h1);
        gemm2_kernel<<<dim3(2, 16), dim3(256), 0, stream>>>(
            h1, W2, b2, n2_gamma, n2_beta, n2_mean, n2_var,
            bk_gamma, bk_beta, bk_mean, bk_var, yv);
        head_kernel<<<dim3(B_), dim3(128), 0, stream>>>(xg2, yv, Wcg, bcg, Wck, bck, out);
    } else {
        float* pooled      = (float*)d_ws;                       // 524288 f
        unsigned char* ids = (unsigned char*)(pooled + 524288);  // 524288 B
        float* xg2         = (float*)(ids + 524288);             // 131072 f
        float* h1          = xg2 + 131072;                       // 524288 f
        float* yv          = h1 + 524288;                        // 131072 f

        pool_kernel<<<dim3((B_ * C_) / 4), dim3(256), 0, stream>>>(x, pooled);
        kmeans_fb_kernel<<<dim3(B_), dim3(512), 0, stream>>>(x, ids);
        gemm1_kernel<<<dim3(8, 4, 5), dim3(256), 0, stream>>>(
            pooled, ids, Wg, bg, g_gamma, g_beta, g_mean, g_var,
            gb_gamma, gb_beta, gb_mean, gb_var, W1, b1,
            n1_gamma, n1_beta, n1_mean, n1_var, xg2, h1);
        gemm2_kernel<<<dim3(2, 16), dim3(256), 0, stream>>>(
            h1, W2, b2, n2_gamma, n2_beta, n2_mean, n2_var,
            bk_gamma, bk_beta, bk_mean, bk_var, yv);
        head_kernel<<<dim3(B_), dim3(128), 0, stream>>>(xg2, yv, Wcg, bcg, Wck, bck, out);
    }
}